// Round 3
// baseline (556.171 us; speedup 1.0000x reference)
//
#include <hip/hip_runtime.h>
#include <hip/hip_cooperative_groups.h>

namespace cg = cooperative_groups;

#define NN 4096
#define NE 8192
#define NLG 32768
#define CAP 32

typedef unsigned int u32;
typedef unsigned short u16;
typedef __attribute__((ext_vector_type(4))) float f32x4;
typedef __attribute__((ext_vector_type(8))) short bf16x8;
typedef __attribute__((ext_vector_type(8))) unsigned short u16x8;
typedef __attribute__((ext_vector_type(4))) unsigned short u16x4;

__device__ __forceinline__ float bf2f(u16 u) { return __uint_as_float(((u32)u) << 16); }
__device__ __forceinline__ u16 f2bf(float f) {
    u32 x = __float_as_uint(f);
    return (u16)((x + 0x7fffu + ((x >> 16) & 1u)) >> 16);  // RNE
}

// ---------------- helpers ----------------
__device__ __forceinline__ void wtrK(const float* src, u16* dst, u32 i, int Kp, int Nw, int ld, int kofs) {
    int nn = i / Kp, kk = i - nn * Kp;
    dst[(size_t)nn * ld + kofs + kk] = f2bf(src[(size_t)kk * Nw + nn]);
}
__device__ __forceinline__ void wtrS(const float* sa, const float* sb, u16* dst, u32 i, int Kp, int Nw, int ld) {
    int nn = i / Kp, kk = i - nn * Kp;
    dst[(size_t)nn * ld + kk] = f2bf(sa[(size_t)kk * Nw + nn] + sb[(size_t)kk * Nw + nn]);
}

struct RSeg { const u32* cnt; const uint2* rb; const u16* src; u16* dst; int ld; int shift; };

__device__ __forceinline__ void spmm_row8(const RSeg& s, int t) {
    int row = t >> s.shift, g = t & ((1 << s.shift) - 1);
    u32 jn = s.cnt[row]; if (jn > CAP) jn = CAP;
    const uint2* bp = s.rb + (size_t)row * CAP;
    const u16* srcg = s.src + g * 8;
    float acc[8] = {};
    u32 j = 0;
    for (; j + 4 <= jn; j += 4) {
        uint2 q0 = bp[j], q1 = bp[j + 1], q2 = bp[j + 2], q3 = bp[j + 3];
        u16x8 x0 = *(const u16x8*)(srcg + (size_t)q0.x * s.ld);
        u16x8 x1 = *(const u16x8*)(srcg + (size_t)q1.x * s.ld);
        u16x8 x2 = *(const u16x8*)(srcg + (size_t)q2.x * s.ld);
        u16x8 x3 = *(const u16x8*)(srcg + (size_t)q3.x * s.ld);
        float w0 = __uint_as_float(q0.y), w1 = __uint_as_float(q1.y);
        float w2 = __uint_as_float(q2.y), w3 = __uint_as_float(q3.y);
#pragma unroll
        for (int e = 0; e < 8; ++e) {
            acc[e] = fmaf(w0, bf2f(x0[e]), acc[e]);
            acc[e] = fmaf(w1, bf2f(x1[e]), acc[e]);
            acc[e] = fmaf(w2, bf2f(x2[e]), acc[e]);
            acc[e] = fmaf(w3, bf2f(x3[e]), acc[e]);
        }
    }
    for (; j < jn; ++j) {
        uint2 q = bp[j];
        u16x8 xv = *(const u16x8*)(srcg + (size_t)q.x * s.ld);
        float w = __uint_as_float(q.y);
#pragma unroll
        for (int e = 0; e < 8; ++e) acc[e] = fmaf(w, bf2f(xv[e]), acc[e]);
    }
    u16x8 o;
#pragma unroll
    for (int e = 0; e < 8; ++e) o[e] = f2bf(acc[e]);
    *(u16x8*)(s.dst + (size_t)row * s.ld + g * 8) = o;
}

struct G { const u16* Aa; int lda; const u16* WT; int K; const float* bias;
           u16* dst; int ldd; };

__device__ __forceinline__ void gemm_do(const G& g, int bx, int ny, int lane) {
    int m0 = bx * 16, n0 = ny * 64;
    int row = lane & 15, koff = (lane >> 4) * 8;
    f32x4 acc[4] = {};
    const u16* Ap = g.Aa + (size_t)(m0 + row) * g.lda + koff;
    const u16* Wp = g.WT + (size_t)(n0 + row) * g.K + koff;
    size_t ws = (size_t)16 * g.K;
    for (int k0 = 0; k0 < g.K; k0 += 32) {
        bf16x8 af = *(const bf16x8*)(Ap + k0);
#pragma unroll
        for (int nt = 0; nt < 4; ++nt) {
            bf16x8 bf = *(const bf16x8*)(Wp + nt * ws + k0);
            acc[nt] = __builtin_amdgcn_mfma_f32_16x16x32_bf16(af, bf, acc[nt], 0, 0, 0);
        }
    }
    int orow = m0 + (lane >> 4) * 4;
#pragma unroll
    for (int nt = 0; nt < 4; ++nt) {
        int col = n0 + nt * 16 + row;
        float bv = g.bias[col];
#pragma unroll
        for (int r = 0; r < 4; ++r) {
            float v = fmaxf(acc[nt][r] + bv, 0.f);  // relu
            g.dst[(size_t)(orow + r) * g.ldd + col] = f2bf(v);
        }
    }
}

// ---------------- mega kernel: whole pipeline, 1 launch, grid.sync between phases ----------------
struct MArgs {
    const float *x, *ex;
    const float *nW0, *nW1, *eWl0, *eWu0, *eWl1, *eWu1, *fnW, *feW, *nb0, *nb1;
    const int *nei, *eil, *eiu;
    const float *eal, *eau;
    const float *eb0, *eb1, *fnb, *feb;
    u32 *cntA, *cntL, *cntU;
    u32 *colA, *colL, *colU, *eidL, *eidU;
    uint2 *rb1A, *rb1L, *rb1U;
    u16 *Zb1n, *Zb1e, *Zb2n, *Zb2e;
    u16 *nW0T, *nW1T, *eW1T, *eW2T, *fnWT, *feWT;
    float *nb0s, *nb1s;
    float *outn, *oute;
};

__global__ __launch_bounds__(256, 4) void mega(MArgs A) {
    __shared__ union {
        struct { uint2 bkt[64][33]; u32 jns[64]; } r;   // resolve+hop1 staging
        u16 g2[2][16 * 128];                            // gemm2 intermediate
    } sh;
    cg::grid_group grid = cg::this_grid();
    const u32 tid = threadIdx.x;
    const u32 gtid = blockIdx.x * blockDim.x + tid;
    const u32 tot = gridDim.x * blockDim.x;

    // ================= P0: prep (converts/transposes/bias) + bucket append =================
    {
        const u32 C0 = 65536;                 // x conv (f32x4 units)
        const u32 C1 = C0 + 65536;            // ex conv
        const u32 C2 = C1 + 24576;            // nW0T (Kp=192)
        const u32 C3 = C2 + 49152;            // nW1T (Kp=384)
        const u32 C4 = C3 + 4096;             // eW1T sum block (Kp=32)
        const u32 C5 = C4 + 4096;             // eWl0 k=1
        const u32 C6 = C5 + 4096;             // eWl0 k=2
        const u32 C7 = C6 + 4096;             // eWu0 k=1
        const u32 C8 = C7 + 4096;             // eWu0 k=2
        const u32 C9 = C8 + 16384;            // eW2T sum block (Kp=128)
        const u32 C10 = C9 + 16384;           // eWl1 k=1
        const u32 C11 = C10 + 16384;          // eWl1 k=2
        const u32 C12 = C11 + 16384;          // eWu1 k=1
        const u32 C13 = C12 + 16384;          // eWu1 k=2
        const u32 C14 = C13 + 8192;           // fnWT
        const u32 C15 = C14 + 8192;           // feWT
        const u32 C16 = C15 + 256;            // bias sums
        const u32 C17 = C16 + (NE + 2 * NLG); // append
        for (u32 i = gtid; i < C17; i += tot) {
            if (i < C0) {
                u32 t = i; int r = t >> 4, c4 = t & 15;
                f32x4 v = *(const f32x4*)(A.x + (size_t)t * 4);
                u16x4 o;
#pragma unroll
                for (int e = 0; e < 4; ++e) o[e] = f2bf(v[e]);
                *(u16x4*)(A.Zb1n + (size_t)r * 192 + c4 * 4) = o;
            } else if (i < C1) {
                u32 t = i - C0; int r = t >> 3, c4 = t & 7;
                f32x4 v = *(const f32x4*)(A.ex + (size_t)t * 4);
                u16x4 o;
#pragma unroll
                for (int e = 0; e < 4; ++e) o[e] = f2bf(v[e]);
                *(u16x4*)(A.Zb1e + (size_t)r * 160 + c4 * 4) = o;
            }
            else if (i < C2)  wtrK(A.nW0, A.nW0T, i - C1, 192, 128, 192, 0);
            else if (i < C3)  wtrK(A.nW1, A.nW1T, i - C2, 384, 128, 384, 0);
            else if (i < C4)  wtrS(A.eWl0, A.eWu0, A.eW1T, i - C3, 32, 128, 160);
            else if (i < C5)  wtrK(A.eWl0 + 32 * 128,     A.eW1T, i - C4, 32, 128, 160, 32);
            else if (i < C6)  wtrK(A.eWl0 + 2 * 32 * 128, A.eW1T, i - C5, 32, 128, 160, 64);
            else if (i < C7)  wtrK(A.eWu0 + 32 * 128,     A.eW1T, i - C6, 32, 128, 160, 96);
            else if (i < C8)  wtrK(A.eWu0 + 2 * 32 * 128, A.eW1T, i - C7, 32, 128, 160, 128);
            else if (i < C9)  wtrS(A.eWl1, A.eWu1, A.eW2T, i - C8, 128, 128, 640);
            else if (i < C10) wtrK(A.eWl1 + 128 * 128,     A.eW2T, i - C9, 128, 128, 640, 128);
            else if (i < C11) wtrK(A.eWl1 + 2 * 128 * 128, A.eW2T, i - C10, 128, 128, 640, 256);
            else if (i < C12) wtrK(A.eWu1 + 128 * 128,     A.eW2T, i - C11, 128, 128, 640, 384);
            else if (i < C13) wtrK(A.eWu1 + 2 * 128 * 128, A.eW2T, i - C12, 128, 128, 640, 512);
            else if (i < C14) wtrK(A.fnW, A.fnWT, i - C13, 128, 64, 128, 0);
            else if (i < C15) wtrK(A.feW, A.feWT, i - C14, 128, 64, 128, 0);
            else if (i < C16) {
                u32 t = i - C15;
                if (t < 128) { float s = 0.f; for (int k = 0; k < 3; ++k) s += A.nb0[k * 128 + t]; A.nb0s[t] = s; }
                else { t -= 128; float s = 0.f; for (int k = 0; k < 3; ++k) s += A.nb1[k * 128 + t]; A.nb1s[t] = s; }
            } else {
                u32 t = i - C16;
                if (t < NE) {
                    int r = A.nei[t];
                    u32 p = atomicAdd(&A.cntA[r], 1u);
                    if (p < CAP) A.colA[r * CAP + p] = (u32)A.nei[NE + t];
                } else if (t < NE + NLG) {
                    u32 e = t - NE;
                    int r = A.eil[e];
                    u32 p = atomicAdd(&A.cntL[r], 1u);
                    if (p < CAP) { A.colL[r * CAP + p] = (u32)A.eil[NLG + e]; A.eidL[r * CAP + p] = e; }
                } else {
                    u32 e = t - NE - NLG;
                    int r = A.eiu[e];
                    u32 p = atomicAdd(&A.cntU[r], 1u);
                    if (p < CAP) { A.colU[r * CAP + p] = (u32)A.eiu[NLG + e]; A.eidU[r * CAP + p] = e; }
                }
            }
        }
    }
    grid.sync();

    // ================= P1: fused resolve + layer-1 hop-1 (block-local, LDS-staged) =================
    // In-place semantics: loser/dup slots get w=0. A: first-slot-wins. L/U: max-eid-wins.
    for (u32 b = blockIdx.x; b < 384; b += gridDim.x) {
        const int seg = (b < 128) ? 0 : (b < 256 ? 1 : 2);   // A / L / U
        const int rowbase = (seg == 0 ? (int)b : (seg == 1 ? (int)b - 128 : (int)b - 256)) * (seg == 0 ? 32 : 64);
        const u32* cnt = seg == 0 ? A.cntA : (seg == 1 ? A.cntL : A.cntU);
        const u32* col = seg == 0 ? A.colA : (seg == 1 ? A.colL : A.colU);
        uint2* rb = seg == 0 ? A.rb1A : (seg == 1 ? A.rb1L : A.rb1U);

        {   // phase A: resolve into LDS + global rb1
            int lr, s, STR;
            if (seg == 0) { lr = tid >> 3; s = tid & 7; STR = 8; }   // 32 rows x 8 slot-threads
            else          { lr = tid >> 2; s = tid & 3; STR = 4; }   // 64 rows x 4 slot-threads
            int row = rowbase + lr;
            u32 jn = cnt[row]; if (jn > CAP) jn = CAP;
            if (s == 0) sh.r.jns[lr] = jn;
            const u32* cp = col + row * CAP;
            if (seg == 0) {
                for (u32 j = s; j < jn; j += STR) {
                    u32 cj = cp[j];
                    float w = 1.0f;
                    for (u32 j2 = 0; j2 < j; ++j2) if (cp[j2] == cj) { w = 0.0f; break; }
                    uint2 v = make_uint2(cj, __float_as_uint(w));
                    sh.r.bkt[lr][j] = v; rb[row * CAP + j] = v;
                }
            } else {
                const u32* ep = (seg == 1 ? A.eidL : A.eidU) + row * CAP;
                const float* wsr = seg == 1 ? A.eal : A.eau;
                for (u32 j = s; j < jn; j += STR) {
                    u32 cj = cp[j], ej = ep[j];
                    float w = wsr[ej];
                    for (u32 j2 = 0; j2 < jn; ++j2)
                        if (j2 != j && cp[j2] == cj && ep[j2] > ej) { w = 0.0f; break; }
                    uint2 v = make_uint2(cj, __float_as_uint(w));
                    sh.r.bkt[lr][j] = v; rb[row * CAP + j] = v;
                }
            }
        }
        __syncthreads();

        {   // phase B: hop-1 gather (width 8) using LDS buckets
            int lr2, g;
            if (seg == 0) { lr2 = tid >> 3; g = tid & 7; }
            else          { lr2 = tid >> 2; g = tid & 3; }
            const int row2 = rowbase + lr2;
            const u16* src = seg == 0 ? A.Zb1n : A.Zb1e;
            u16* dst = seg == 0 ? A.Zb1n + 64 : (seg == 1 ? A.Zb1e + 32 : A.Zb1e + 96);
            const int ld = seg == 0 ? 192 : 160;
            const u32 jn2 = sh.r.jns[lr2];
            const u16* srcg = src + g * 8;
            float acc[8] = {};
            for (u32 j = 0; j < jn2; ++j) {
                uint2 q = sh.r.bkt[lr2][j];
                u16x8 xv = *(const u16x8*)(srcg + (size_t)q.x * ld);
                float w = __uint_as_float(q.y);
#pragma unroll
                for (int e = 0; e < 8; ++e) acc[e] = fmaf(w, bf2f(xv[e]), acc[e]);
            }
            u16x8 o;
#pragma unroll
            for (int e = 0; e < 8; ++e) o[e] = f2bf(acc[e]);
            *(u16x8*)(dst + (size_t)row2 * ld + g * 8) = o;
        }
        __syncthreads();   // protect LDS before any next loop iteration
    }
    grid.sync();

    // ================= P2: layer-1 hop-2 (chained, width 8) =================
    {
        const u32 nA = NN << 3, nL = NE << 2;
        for (u32 t = gtid; t < nA + 2 * nL; t += tot) {
            if (t < nA)            spmm_row8(RSeg{A.cntA, A.rb1A, A.Zb1n + 64, A.Zb1n + 128, 192, 3}, t);
            else if (t < nA + nL)  spmm_row8(RSeg{A.cntL, A.rb1L, A.Zb1e + 32, A.Zb1e + 64,  160, 2}, t - nA);
            else                   spmm_row8(RSeg{A.cntU, A.rb1U, A.Zb1e + 96, A.Zb1e + 128, 160, 2}, t - nA - nL);
        }
    }
    grid.sync();

    // ================= P3: layer-1 GEMMs =================
    {
        G g0{A.Zb1n, 192, A.nW0T, 192, A.nb0s, A.Zb2n, 384};
        G g1{A.Zb1e, 160, A.eW1T, 160, A.eb0,  A.Zb2e, 640};
        int wv = tid >> 6, lane = tid & 63;
        for (u32 u = blockIdx.x; u < 384; u += gridDim.x) {
            int ny = u / 192, bx = u % 192;
            int bxg = bx * 4 + wv;
            if (bxg < 256) gemm_do(g0, bxg, ny, lane);
            else gemm_do(g1, bxg - 256, ny, lane);
        }
    }
    grid.sync();

    // ================= P4: layer-2 hop-1 (width 8) =================
    {
        const u32 nA = NN << 4, nL = NE << 4;
        for (u32 t = gtid; t < nA + 2 * nL; t += tot) {
            if (t < nA)            spmm_row8(RSeg{A.cntA, A.rb1A, A.Zb2n,       A.Zb2n + 128, 384, 4}, t);
            else if (t < nA + nL)  spmm_row8(RSeg{A.cntL, A.rb1L, A.Zb2e,       A.Zb2e + 128, 640, 4}, t - nA);
            else                   spmm_row8(RSeg{A.cntU, A.rb1U, A.Zb2e,       A.Zb2e + 384, 640, 4}, t - nA - nL);
        }
    }
    grid.sync();

    // ================= P5: layer-2 hop-2 (chained, width 8) =================
    {
        const u32 nA = NN << 4, nL = NE << 4;
        for (u32 t = gtid; t < nA + 2 * nL; t += tot) {
            if (t < nA)            spmm_row8(RSeg{A.cntA, A.rb1A, A.Zb2n + 128, A.Zb2n + 256, 384, 4}, t);
            else if (t < nA + nL)  spmm_row8(RSeg{A.cntL, A.rb1L, A.Zb2e + 128, A.Zb2e + 256, 640, 4}, t - nA);
            else                   spmm_row8(RSeg{A.cntU, A.rb1U, A.Zb2e + 384, A.Zb2e + 512, 640, 4}, t - nA - nL);
        }
    }
    grid.sync();

    // ================= P6: fused layer-2 GEMM + output head =================
    {
        int wv = tid >> 6, lane = tid & 63;
        int tile = wv >> 1, half = wv & 1;
        int c = lane & 15, q = lane >> 4, koff = q * 8;
        for (u32 u = blockIdx.x; u < 384; u += gridDim.x) {
            int s = (int)u * 2 + tile;                    // 0..767 row-tiles
            const u16 *Ab, *WT, *hWT; const float *bias, *hB; float* outp; int lda, K, m0;
            if (s < 256) { Ab = A.Zb2n; lda = 384; K = 384; WT = A.nW1T; bias = A.nb1s;
                           hWT = A.fnWT; hB = A.fnb; outp = A.outn; m0 = s * 16; }
            else { int t2 = s - 256; Ab = A.Zb2e; lda = 640; K = 640; WT = A.eW2T; bias = A.eb1;
                   hWT = A.feWT; hB = A.feb; outp = A.oute; m0 = t2 * 16; }
            u16* L = sh.g2[tile];
            const u16* Ap = Ab + (size_t)(m0 + c) * lda + koff;

            f32x4 acc[4] = {};
            const u16* Wp = WT + (size_t)(half * 64 + c) * K + koff;
            size_t ws = (size_t)16 * K;
            for (int k0 = 0; k0 < K; k0 += 32) {
                bf16x8 af = *(const bf16x8*)(Ap + k0);
#pragma unroll
                for (int nt = 0; nt < 4; ++nt) {
                    bf16x8 bf = *(const bf16x8*)(Wp + nt * ws + k0);
                    acc[nt] = __builtin_amdgcn_mfma_f32_16x16x32_bf16(af, bf, acc[nt], 0, 0, 0);
                }
            }
#pragma unroll
            for (int nt = 0; nt < 4; ++nt) {
                int col = half * 64 + nt * 16 + c;
                float bv = bias[col];
#pragma unroll
                for (int r = 0; r < 4; ++r)
                    L[(q * 4 + r) * 128 + col] = f2bf(fmaxf(acc[nt][r] + bv, 0.f));
            }
            __syncthreads();

            f32x4 hacc[2] = {};
            const u16* Hp = hWT + (size_t)c * 128 + koff;
#pragma unroll
            for (int k0 = 0; k0 < 128; k0 += 32) {
                bf16x8 af = *(const bf16x8*)(L + c * 128 + koff + k0);
#pragma unroll
                for (int t2 = 0; t2 < 2; ++t2) {
                    int nt = half * 2 + t2;
                    bf16x8 bf = *(const bf16x8*)(Hp + nt * 16 * 128 + k0);
                    hacc[t2] = __builtin_amdgcn_mfma_f32_16x16x32_bf16(af, bf, hacc[t2], 0, 0, 0);
                }
            }
#pragma unroll
            for (int t2 = 0; t2 < 2; ++t2) {
                int nt = half * 2 + t2;
                int col = nt * 16 + c;
                float bv = hB[col];
#pragma unroll
                for (int r = 0; r < 4; ++r)
                    outp[(size_t)(m0 + q * 4 + r) * 64 + col] = hacc[t2][r] + bv;
            }
            __syncthreads();   // protect LDS before next loop iteration
        }
    }
}

// ================= launch =================
extern "C" void kernel_launch(void* const* d_in, const int* in_sizes, int n_in,
                              void* d_out, int out_size, void* d_ws, size_t ws_size,
                              hipStream_t stream)
{
    const float* x    = (const float*)d_in[0];
    const float* ex   = (const float*)d_in[1];
    const int*   nei  = (const int*)d_in[2];
    const int*   eil  = (const int*)d_in[3];
    const float* eal  = (const float*)d_in[4];
    const int*   eiu  = (const int*)d_in[5];
    const float* eau  = (const float*)d_in[6];
    const float* nW0  = (const float*)d_in[7];
    const float* nb0  = (const float*)d_in[8];
    const float* nW1  = (const float*)d_in[9];
    const float* nb1  = (const float*)d_in[10];
    const float* fnW  = (const float*)d_in[11];
    const float* fnb  = (const float*)d_in[12];
    const float* eWl0 = (const float*)d_in[13];
    const float* eWu0 = (const float*)d_in[14];
    const float* eb0  = (const float*)d_in[15];
    const float* eWl1 = (const float*)d_in[16];
    const float* eWu1 = (const float*)d_in[17];
    const float* eb1  = (const float*)d_in[18];
    const float* feW  = (const float*)d_in[19];
    const float* feb  = (const float*)d_in[20];

    char* wsb = (char*)d_ws;
    size_t off = 0;
    auto alloc = [&](size_t bytes) { void* p = wsb + off; off += (bytes + 255) & ~(size_t)255; return p; };

    // ---- zeroed region (single small memset): raw append counters only ----
    u32* cntA = (u32*)alloc(NN * 4);
    u32* cntL = (u32*)alloc(NE * 4);
    u32* cntU = (u32*)alloc(NE * 4);
    size_t zbytes = off;   // ~82 KB

    uint2* rb1A = (uint2*)alloc((size_t)NN * CAP * 8);
    uint2* rb1L = (uint2*)alloc((size_t)NE * CAP * 8);
    uint2* rb1U = (uint2*)alloc((size_t)NE * CAP * 8);

    u32* colA = (u32*)alloc((size_t)NN * CAP * 4);
    u32* colL = (u32*)alloc((size_t)NE * CAP * 4);
    u32* colU = (u32*)alloc((size_t)NE * CAP * 4);
    u32* eidL = (u32*)alloc((size_t)NE * CAP * 4);
    u32* eidU = (u32*)alloc((size_t)NE * CAP * 4);

    u16* Zb1n = (u16*)alloc((size_t)4096 * 192 * 2);
    u16* Zb1e = (u16*)alloc((size_t)8192 * 160 * 2);
    u16* Zb2n = (u16*)alloc((size_t)4096 * 384 * 2);
    u16* Zb2e = (u16*)alloc((size_t)8192 * 640 * 2);

    u16* nW0T = (u16*)alloc((size_t)128 * 192 * 2);
    u16* nW1T = (u16*)alloc((size_t)128 * 384 * 2);
    u16* eW1T = (u16*)alloc((size_t)128 * 160 * 2);
    u16* eW2T = (u16*)alloc((size_t)128 * 640 * 2);
    u16* fnWT = (u16*)alloc((size_t)64 * 128 * 2);
    u16* feWT = (u16*)alloc((size_t)64 * 128 * 2);
    float* nb0s = (float*)alloc(128 * 4);
    float* nb1s = (float*)alloc(128 * 4);

    // ---- D0: zero counters (~82 KB) ----
    hipMemsetAsync(d_ws, 0, zbytes, stream);

    // ---- D1: the whole pipeline, cooperative ----
    static int gblocks = 0;
    if (gblocks == 0) {
        int bpm = 0;
        hipError_t e = hipOccupancyMaxActiveBlocksPerMultiprocessor(&bpm, (const void*)mega, 256, 0);
        if (e != hipSuccess || bpm < 1) bpm = 1;
        gblocks = bpm * 256;            // 256 CUs on MI355X
        if (gblocks > 1024) gblocks = 1024;
        if (gblocks < 256) gblocks = 256;
    }

    MArgs M{x, ex, nW0, nW1, eWl0, eWu0, eWl1, eWu1, fnW, feW, nb0, nb1,
            nei, eil, eiu, eal, eau, eb0, eb1, fnb, feb,
            cntA, cntL, cntU, colA, colL, colU, eidL, eidU,
            rb1A, rb1L, rb1U, Zb1n, Zb1e, Zb2n, Zb2e,
            nW0T, nW1T, eW1T, eW2T, fnWT, feWT, nb0s, nb1s,
            (float*)d_out, (float*)d_out + 262144};
    void* kargs[] = { (void*)&M };
    hipLaunchCooperativeKernel((const void*)mega, dim3(gblocks), dim3(256), kargs, 0, stream);
}

// Round 5
// 168.410 us; speedup vs baseline: 3.3025x; 3.3025x over previous
//
#include <hip/hip_runtime.h>

#define NN 4096
#define NE 8192
#define NLG 32768
#define CAP 32

typedef unsigned int u32;
typedef unsigned short u16;
typedef __attribute__((ext_vector_type(4))) float f32x4;
typedef __attribute__((ext_vector_type(8))) short bf16x8;
typedef __attribute__((ext_vector_type(8))) unsigned short u16x8;
typedef __attribute__((ext_vector_type(4))) unsigned short u16x4;

__device__ __forceinline__ float bf2f(u16 u) { return __uint_as_float(((u32)u) << 16); }
__device__ __forceinline__ u16 f2bf(float f) {
    u32 x = __float_as_uint(f);
    return (u16)((x + 0x7fffu + ((x >> 16) & 1u)) >> 16);  // RNE
}

// ================= K1: prep (converts/transposes/bias) + bucket append, fused =================
struct PAArgs {
    const float *x, *ex;
    const float *nW0, *nW1, *eWl0, *eWu0, *eWl1, *eWu1, *fnW, *feW, *nb0, *nb1;
    const int *nei, *eil, *eiu;
    u32 *cntA, *cntL, *cntU;            // raw counters (zeroed by memset)
    u32 *colA, *colL, *colU, *eidL, *eidU;
    u16 *Zb1n, *Zb1e, *nW0T, *nW1T, *eW1T, *eW2T, *fnWT, *feWT;
    float *nb0s, *nb1s;
};

__device__ __forceinline__ void wtrK(const float* src, u16* dst, u32 i, int Kp, int Nw, int ld, int kofs) {
    int nn = i / Kp, kk = i - nn * Kp;
    dst[(size_t)nn * ld + kofs + kk] = f2bf(src[(size_t)kk * Nw + nn]);
}
__device__ __forceinline__ void wtrS(const float* sa, const float* sb, u16* dst, u32 i, int Kp, int Nw, int ld) {
    int nn = i / Kp, kk = i - nn * Kp;
    dst[(size_t)nn * ld + kk] = f2bf(sa[(size_t)kk * Nw + nn] + sb[(size_t)kk * Nw + nn]);
}

__global__ __launch_bounds__(256) void prep_append(PAArgs A) {
    const u32 gid = blockIdx.x * blockDim.x + threadIdx.x;
    const u32 gsz = gridDim.x * blockDim.x;
    const u32 C0 = 65536;                 // x conv (f32x4 units)
    const u32 C1 = C0 + 65536;            // ex conv
    const u32 C2 = C1 + 24576;            // nW0T (Kp=192)
    const u32 C3 = C2 + 49152;            // nW1T (Kp=384)
    const u32 C4 = C3 + 4096;             // eW1T sum block (Kp=32)
    const u32 C5 = C4 + 4096;             // eWl0 k=1
    const u32 C6 = C5 + 4096;             // eWl0 k=2
    const u32 C7 = C6 + 4096;             // eWu0 k=1
    const u32 C8 = C7 + 4096;             // eWu0 k=2
    const u32 C9 = C8 + 16384;            // eW2T sum block (Kp=128)
    const u32 C10 = C9 + 16384;           // eWl1 k=1
    const u32 C11 = C10 + 16384;          // eWl1 k=2
    const u32 C12 = C11 + 16384;          // eWu1 k=1
    const u32 C13 = C12 + 16384;          // eWu1 k=2
    const u32 C14 = C13 + 8192;           // fnWT
    const u32 C15 = C14 + 8192;           // feWT
    const u32 C16 = C15 + 256;            // bias sums
    const u32 C17 = C16 + (NE + 2 * NLG); // append
    for (u32 i = gid; i < C17; i += gsz) {
        if (i < C0) {
            u32 t = i; int r = t >> 4, c4 = t & 15;
            f32x4 v = *(const f32x4*)(A.x + (size_t)t * 4);
            u16x4 o;
#pragma unroll
            for (int e = 0; e < 4; ++e) o[e] = f2bf(v[e]);
            *(u16x4*)(A.Zb1n + (size_t)r * 192 + c4 * 4) = o;
        } else if (i < C1) {
            u32 t = i - C0; int r = t >> 3, c4 = t & 7;
            f32x4 v = *(const f32x4*)(A.ex + (size_t)t * 4);
            u16x4 o;
#pragma unroll
            for (int e = 0; e < 4; ++e) o[e] = f2bf(v[e]);
            *(u16x4*)(A.Zb1e + (size_t)r * 160 + c4 * 4) = o;
        }
        else if (i < C2)  wtrK(A.nW0, A.nW0T, i - C1, 192, 128, 192, 0);
        else if (i < C3)  wtrK(A.nW1, A.nW1T, i - C2, 384, 128, 384, 0);
        else if (i < C4)  wtrS(A.eWl0, A.eWu0, A.eW1T, i - C3, 32, 128, 160);
        else if (i < C5)  wtrK(A.eWl0 + 32 * 128,     A.eW1T, i - C4, 32, 128, 160, 32);
        else if (i < C6)  wtrK(A.eWl0 + 2 * 32 * 128, A.eW1T, i - C5, 32, 128, 160, 64);
        else if (i < C7)  wtrK(A.eWu0 + 32 * 128,     A.eW1T, i - C6, 32, 128, 160, 96);
        else if (i < C8)  wtrK(A.eWu0 + 2 * 32 * 128, A.eW1T, i - C7, 32, 128, 160, 128);
        else if (i < C9)  wtrS(A.eWl1, A.eWu1, A.eW2T, i - C8, 128, 128, 640);
        else if (i < C10) wtrK(A.eWl1 + 128 * 128,     A.eW2T, i - C9, 128, 128, 640, 128);
        else if (i < C11) wtrK(A.eWl1 + 2 * 128 * 128, A.eW2T, i - C10, 128, 128, 640, 256);
        else if (i < C12) wtrK(A.eWu1 + 128 * 128,     A.eW2T, i - C11, 128, 128, 640, 384);
        else if (i < C13) wtrK(A.eWu1 + 2 * 128 * 128, A.eW2T, i - C12, 128, 128, 640, 512);
        else if (i < C14) wtrK(A.fnW, A.fnWT, i - C13, 128, 64, 128, 0);
        else if (i < C15) wtrK(A.feW, A.feWT, i - C14, 128, 64, 128, 0);
        else if (i < C16) {
            u32 t = i - C15;
            if (t < 128) { float s = 0.f; for (int k = 0; k < 3; ++k) s += A.nb0[k * 128 + t]; A.nb0s[t] = s; }
            else { t -= 128; float s = 0.f; for (int k = 0; k < 3; ++k) s += A.nb1[k * 128 + t]; A.nb1s[t] = s; }
        } else {
            u32 t = i - C16;
            if (t < NE) {
                int r = A.nei[t];
                u32 p = atomicAdd(&A.cntA[r], 1u);
                if (p < CAP) A.colA[r * CAP + p] = (u32)A.nei[NE + t];
            } else if (t < NE + NLG) {
                u32 e = t - NE;
                int r = A.eil[e];
                u32 p = atomicAdd(&A.cntL[r], 1u);
                if (p < CAP) { A.colL[r * CAP + p] = (u32)A.eil[NLG + e]; A.eidL[r * CAP + p] = e; }
            } else {
                u32 e = t - NE - NLG;
                int r = A.eiu[e];
                u32 p = atomicAdd(&A.cntU[r], 1u);
                if (p < CAP) { A.colU[r * CAP + p] = (u32)A.eiu[NLG + e]; A.eidU[r * CAP + p] = e; }
            }
        }
    }
}

// ================= K2: fused resolve + layer-1 hop-1 spmm =================
// In-place semantics: loser/dup slots get w=0. A: first-slot-wins. L/U: max-eid-wins.
struct RHArgs {
    const u32 *cntA, *cntL, *cntU;
    const u32 *colA, *colL, *colU, *eidL, *eidU;
    const float *eal, *eau;
    uint2 *rb1A, *rb1L, *rb1U;
    u16 *Zb1n, *Zb1e;
};

__global__ __launch_bounds__(256) void resolve_hop1(RHArgs A) {
    __shared__ uint2 bkt[64][33];   // +1 pad: breaks 256B-stride bank aliasing
    __shared__ u32 jns[64];
    const int b = blockIdx.x, tid = threadIdx.x;
    const int seg = (b < 128) ? 0 : (b < 256 ? 1 : 2);   // A / L / U
    const int rowbase = (seg == 0 ? b : (seg == 1 ? b - 128 : b - 256)) * (seg == 0 ? 32 : 64);
    const u32* cnt = seg == 0 ? A.cntA : (seg == 1 ? A.cntL : A.cntU);
    const u32* col = seg == 0 ? A.colA : (seg == 1 ? A.colL : A.colU);
    uint2* rb = seg == 0 ? A.rb1A : (seg == 1 ? A.rb1L : A.rb1U);

    // ---- phase A: resolve into LDS + global rb1 ----
    {
        int lr, s, STR;
        if (seg == 0) { lr = tid >> 3; s = tid & 7; STR = 8; }   // 32 rows x 8 slot-threads
        else          { lr = tid >> 2; s = tid & 3; STR = 4; }   // 64 rows x 4 slot-threads
        int row = rowbase + lr;
        u32 jn = cnt[row]; if (jn > CAP) jn = CAP;
        if (s == 0) jns[lr] = jn;
        const u32* cp = col + row * CAP;
        if (seg == 0) {
            for (u32 j = s; j < jn; j += STR) {
                u32 cj = cp[j];
                float w = 1.0f;
                for (u32 j2 = 0; j2 < j; ++j2) if (cp[j2] == cj) { w = 0.0f; break; }
                uint2 v = make_uint2(cj, __float_as_uint(w));
                bkt[lr][j] = v; rb[row * CAP + j] = v;
            }
        } else {
            const u32* ep = (seg == 1 ? A.eidL : A.eidU) + row * CAP;
            const float* wsr = seg == 1 ? A.eal : A.eau;
            for (u32 j = s; j < jn; j += STR) {
                u32 cj = cp[j], ej = ep[j];
                float w = wsr[ej];
                for (u32 j2 = 0; j2 < jn; ++j2)
                    if (j2 != j && cp[j2] == cj && ep[j2] > ej) { w = 0.0f; break; }
                uint2 v = make_uint2(cj, __float_as_uint(w));
                bkt[lr][j] = v; rb[row * CAP + j] = v;
            }
        }
    }
    __syncthreads();

    // ---- phase B: hop-1 gather (width 8) using LDS buckets ----
    int lr2, g;
    if (seg == 0) { lr2 = tid >> 3; g = tid & 7; }   // 32 rows x 8 groups (64 cols)
    else          { lr2 = tid >> 2; g = tid & 3; }   // 64 rows x 4 groups (32 cols)
    const int row2 = rowbase + lr2;
    const u16* src = seg == 0 ? A.Zb1n : A.Zb1e;
    u16* dst = seg == 0 ? A.Zb1n + 64 : (seg == 1 ? A.Zb1e + 32 : A.Zb1e + 96);
    const int ld = seg == 0 ? 192 : 160;
    const u32 jn2 = jns[lr2];
    const u16* srcg = src + g * 8;
    float acc[8] = {};
    for (u32 j = 0; j < jn2; ++j) {
        uint2 q = bkt[lr2][j];
        u16x8 xv = *(const u16x8*)(srcg + (size_t)q.x * ld);
        float w = __uint_as_float(q.y);
#pragma unroll
        for (int e = 0; e < 8; ++e) acc[e] = fmaf(w, bf2f(xv[e]), acc[e]);
    }
    u16x8 o;
#pragma unroll
    for (int e = 0; e < 8; ++e) o[e] = f2bf(acc[e]);
    *(u16x8*)(dst + (size_t)row2 * ld + g * 8) = o;
}

// ================= one-hop gather SpMM over resolved buckets (layer-2 hop-1) =================
struct RSeg { const u32* cnt; const uint2* rb; const u16* src; u16* dst; int n; int shift; int ld; };
struct Seg3 { RSeg s[3]; };

__device__ __forceinline__ void spmm_row8(const RSeg& s, int t) {
    int row = t >> s.shift, g = t & ((1 << s.shift) - 1);
    u32 jn = s.cnt[row]; if (jn > CAP) jn = CAP;
    const uint2* bp = s.rb + (size_t)row * CAP;
    const u16* srcg = s.src + g * 8;
    float acc[8] = {};
    u32 j = 0;
    for (; j + 4 <= jn; j += 4) {
        uint2 q0 = bp[j], q1 = bp[j + 1], q2 = bp[j + 2], q3 = bp[j + 3];
        u16x8 x0 = *(const u16x8*)(srcg + (size_t)q0.x * s.ld);
        u16x8 x1 = *(const u16x8*)(srcg + (size_t)q1.x * s.ld);
        u16x8 x2 = *(const u16x8*)(srcg + (size_t)q2.x * s.ld);
        u16x8 x3 = *(const u16x8*)(srcg + (size_t)q3.x * s.ld);
        float w0 = __uint_as_float(q0.y), w1 = __uint_as_float(q1.y);
        float w2 = __uint_as_float(q2.y), w3 = __uint_as_float(q3.y);
#pragma unroll
        for (int e = 0; e < 8; ++e) {
            acc[e] = fmaf(w0, bf2f(x0[e]), acc[e]);
            acc[e] = fmaf(w1, bf2f(x1[e]), acc[e]);
            acc[e] = fmaf(w2, bf2f(x2[e]), acc[e]);
            acc[e] = fmaf(w3, bf2f(x3[e]), acc[e]);
        }
    }
    for (; j < jn; ++j) {
        uint2 q = bp[j];
        u16x8 xv = *(const u16x8*)(srcg + (size_t)q.x * s.ld);
        float w = __uint_as_float(q.y);
#pragma unroll
        for (int e = 0; e < 8; ++e) acc[e] = fmaf(w, bf2f(xv[e]), acc[e]);
    }
    u16x8 o;
#pragma unroll
    for (int e = 0; e < 8; ++e) o[e] = f2bf(acc[e]);
    *(u16x8*)(s.dst + (size_t)row * s.ld + g * 8) = o;
}

__global__ __launch_bounds__(256) void spmm8_kernel(Seg3 P) {
    int id = blockIdx.x * blockDim.x + threadIdx.x;
    int base = 0;
#pragma unroll
    for (int i = 0; i < 3; ++i) {
        int n = P.s[i].n;
        if (id < base + n) { spmm_row8(P.s[i], id - base); return; }
        base += n;
    }
}

// ================= K4: layer-1 GEMM with fused hop-2 (LDS staging) =================
// Each wave stages its own 16-row tile's hop-2 columns into LDS (gather of hop-1,
// globally visible after resolve_hop1), then runs split-K MFMA:
// node A-tile: k[0,128) global (x|hop1), k[128,192) LDS (hop2)
// edge A-tile: k[0,64) g, k[64,96) LDS(L2), k[96,128) g, k[128,160) LDS(U2)
struct G1Args {
    const u16 *Zb1n, *Zb1e, *nW0T, *eW1T;
    const float *nb0s, *eb0;
    const u32 *cntA, *cntL, *cntU;
    const uint2 *rb1A, *rb1L, *rb1U;
    u16 *Zb2n, *Zb2e;
};

__global__ __launch_bounds__(256) void gemm1_kernel(G1Args A) {
    __shared__ u16 h2[4][16][72];   // stride 72: fragment reads land 2-way (free)
    const int wv = threadIdx.x >> 6, lane = threadIdx.x & 63;
    const int bxg = blockIdx.x * 4 + wv;
    const int ny = blockIdx.y;
    const bool node = bxg < 256;
    const int m0 = (node ? bxg : bxg - 256) * 16;

    // ---- stage hop2 for this wave's tile ----
    {
        const int lr = lane >> 2, g = lane & 3;
        const u32* cnt; const uint2* rb; const u16* src; int ld, dc;
        if (node) { cnt = A.cntA; rb = A.rb1A; src = A.Zb1n + 64 + g * 16; ld = 192; dc = g * 16; }
        else {
            const bool isL = g < 2; const int gg = isL ? g : g - 2;
            cnt = isL ? A.cntL : A.cntU; rb = isL ? A.rb1L : A.rb1U;
            src = (isL ? A.Zb1e + 32 : A.Zb1e + 96) + gg * 16; ld = 160;
            dc = (isL ? 0 : 32) + gg * 16;
        }
        const int row = m0 + lr;
        u32 jn = cnt[row]; if (jn > CAP) jn = CAP;
        const uint2* bp = rb + (size_t)row * CAP;
        float acc[16] = {};
        for (u32 j = 0; j < jn; ++j) {
            uint2 qe = bp[j];
            float w = __uint_as_float(qe.y);
            const u16* p = src + (size_t)qe.x * ld;
            u16x8 a0 = *(const u16x8*)p, a1 = *(const u16x8*)(p + 8);
#pragma unroll
            for (int e = 0; e < 8; ++e) {
                acc[e]     = fmaf(w, bf2f(a0[e]), acc[e]);
                acc[8 + e] = fmaf(w, bf2f(a1[e]), acc[8 + e]);
            }
        }
        u16x8 o0, o1;
#pragma unroll
        for (int e = 0; e < 8; ++e) { o0[e] = f2bf(acc[e]); o1[e] = f2bf(acc[8 + e]); }
        *(u16x8*)&h2[wv][lr][dc] = o0;
        *(u16x8*)&h2[wv][lr][dc + 8] = o1;
    }
    __syncthreads();   // defensive: staging->read ordering (same-wave DS order would suffice)

    // ---- MFMA GEMM, split-K ----
    const int row = lane & 15, koff = (lane >> 4) * 8;
    const int n0 = ny * 64;
    f32x4 acc[4] = {};
    const u16* Lr = &h2[wv][row][koff];
    if (node) {
        const u16* Ap = A.Zb1n + (size_t)(m0 + row) * 192 + koff;
        const u16* Wp = A.nW0T + (size_t)(n0 + row) * 192 + koff;
        const size_t ws = (size_t)16 * 192;
#pragma unroll
        for (int k0 = 0; k0 < 128; k0 += 32) {
            bf16x8 af = *(const bf16x8*)(Ap + k0);
#pragma unroll
            for (int nt = 0; nt < 4; ++nt)
                acc[nt] = __builtin_amdgcn_mfma_f32_16x16x32_bf16(af, *(const bf16x8*)(Wp + nt * ws + k0), acc[nt], 0, 0, 0);
        }
#pragma unroll
        for (int k0 = 128; k0 < 192; k0 += 32) {
            bf16x8 af = *(const bf16x8*)(Lr + (k0 - 128));
#pragma unroll
            for (int nt = 0; nt < 4; ++nt)
                acc[nt] = __builtin_amdgcn_mfma_f32_16x16x32_bf16(af, *(const bf16x8*)(Wp + nt * ws + k0), acc[nt], 0, 0, 0);
        }
        const int orow = m0 + (lane >> 4) * 4;
#pragma unroll
        for (int nt = 0; nt < 4; ++nt) {
            int col = n0 + nt * 16 + row;
            float bv = A.nb0s[col];
#pragma unroll
            for (int r = 0; r < 4; ++r)
                A.Zb2n[(size_t)(orow + r) * 384 + col] = f2bf(fmaxf(acc[nt][r] + bv, 0.f));
        }
    } else {
        const u16* Ap = A.Zb1e + (size_t)(m0 + row) * 160 + koff;
        const u16* Wp = A.eW1T + (size_t)(n0 + row) * 160 + koff;
        const size_t ws = (size_t)16 * 160;
        bf16x8 af;
        af = *(const bf16x8*)(Ap + 0);
#pragma unroll
        for (int nt = 0; nt < 4; ++nt)
            acc[nt] = __builtin_amdgcn_mfma_f32_16x16x32_bf16(af, *(const bf16x8*)(Wp + nt * ws + 0), acc[nt], 0, 0, 0);
        af = *(const bf16x8*)(Ap + 32);
#pragma unroll
        for (int nt = 0; nt < 4; ++nt)
            acc[nt] = __builtin_amdgcn_mfma_f32_16x16x32_bf16(af, *(const bf16x8*)(Wp + nt * ws + 32), acc[nt], 0, 0, 0);
        af = *(const bf16x8*)(Lr + 0);      // L2 hop2, kabs 64
#pragma unroll
        for (int nt = 0; nt < 4; ++nt)
            acc[nt] = __builtin_amdgcn_mfma_f32_16x16x32_bf16(af, *(const bf16x8*)(Wp + nt * ws + 64), acc[nt], 0, 0, 0);
        af = *(const bf16x8*)(Ap + 96);
#pragma unroll
        for (int nt = 0; nt < 4; ++nt)
            acc[nt] = __builtin_amdgcn_mfma_f32_16x16x32_bf16(af, *(const bf16x8*)(Wp + nt * ws + 96), acc[nt], 0, 0, 0);
        af = *(const bf16x8*)(Lr + 32);     // U2 hop2, kabs 128
#pragma unroll
        for (int nt = 0; nt < 4; ++nt)
            acc[nt] = __builtin_amdgcn_mfma_f32_16x16x32_bf16(af, *(const bf16x8*)(Wp + nt * ws + 128), acc[nt], 0, 0, 0);
        const int orow = m0 + (lane >> 4) * 4;
#pragma unroll
        for (int nt = 0; nt < 4; ++nt) {
            int col = n0 + nt * 16 + row;
            float bv = A.eb0[col];
#pragma unroll
            for (int r = 0; r < 4; ++r)
                A.Zb2e[(size_t)(orow + r) * 640 + col] = f2bf(fmaxf(acc[nt][r] + bv, 0.f));
        }
    }
}

// ================= K6: layer-2 GEMM + head with fused hop-2 =================
// Block = 2 tiles x 2 N-halves. Waves (0,1)/(2,3) stage their tile's hop-2 into
// LDS (gather of layer-2 hop-1 from global), one barrier, then split-K MFMA:
// node: k[0,256) global (h|hop1), k[256,384) LDS
// edge: k[0,256) g, k[256,384) LDS(L2), k[384,512) g, k[512,640) LDS(U2)
struct G2Args {
    const u16 *Zb2n, *Zb2e, *nW1T, *eW2T, *fnWT, *feWT;
    const float *nb1s, *eb1, *fnb, *feb;
    const u32 *cntA, *cntL, *cntU;
    const uint2 *rb1A, *rb1L, *rb1U;
    float *outn, *oute;
};

__global__ __launch_bounds__(256) void gemm2_head(G2Args A) {
    __shared__ u16 h2[2][16][264];   // stride 264: fragment reads land 2-way
    __shared__ u16 g2[2][16 * 128];
    const int wv = threadIdx.x >> 6, lane = threadIdx.x & 63;
    const int tile = wv >> 1, half = wv & 1;
    const int s = blockIdx.x * 2 + tile;
    const bool node = s < 256;
    const int m0 = (node ? s : s - 256) * 16;

    // ---- stage hop2 (2 waves per tile) ----
    {
        const int lid = half * 64 + lane;   // 0..127 within tile
        const int lr = lid >> 3, g = lid & 7;
        const int row = m0 + lr;
        if (node) {
            u32 jn = A.cntA[row]; if (jn > CAP) jn = CAP;
            const uint2* bp = A.rb1A + (size_t)row * CAP;
            const u16* src = A.Zb2n + 128 + g * 16;
            float acc[16] = {};
            for (u32 j = 0; j < jn; ++j) {
                uint2 qe = bp[j]; float w = __uint_as_float(qe.y);
                const u16* p = src + (size_t)qe.x * 384;
                u16x8 a0 = *(const u16x8*)p, a1 = *(const u16x8*)(p + 8);
#pragma unroll
                for (int e = 0; e < 8; ++e) {
                    acc[e]     = fmaf(w, bf2f(a0[e]), acc[e]);
                    acc[8 + e] = fmaf(w, bf2f(a1[e]), acc[8 + e]);
                }
            }
            u16x8 o0, o1;
#pragma unroll
            for (int e = 0; e < 8; ++e) { o0[e] = f2bf(acc[e]); o1[e] = f2bf(acc[8 + e]); }
            *(u16x8*)&h2[tile][lr][g * 16] = o0;
            *(u16x8*)&h2[tile][lr][g * 16 + 8] = o1;
        } else {
#pragma unroll
            for (int m = 0; m < 2; ++m) {   // m=0: L2, m=1: U2
                const u32* cnt = m == 0 ? A.cntL : A.cntU;
                const uint2* rb = m == 0 ? A.rb1L : A.rb1U;
                const u16* src = (m == 0 ? A.Zb2e + 128 : A.Zb2e + 384) + g * 16;
                u32 jn = cnt[row]; if (jn > CAP) jn = CAP;
                const uint2* bp = rb + (size_t)row * CAP;
                float acc[16] = {};
                for (u32 j = 0; j < jn; ++j) {
                    uint2 qe = bp[j]; float w = __uint_as_float(qe.y);
                    const u16* p = src + (size_t)qe.x * 640;
                    u16x8 a0 = *(const u16x8*)p, a1 = *(const u16x8*)(p + 8);
#pragma unroll
                    for (int e = 0; e < 8; ++e) {
                        acc[e]     = fmaf(w, bf2f(a0[e]), acc[e]);
                        acc[8 + e] = fmaf(w, bf2f(a1[e]), acc[8 + e]);
                    }
                }
                u16x8 o0, o1;
#pragma unroll
                for (int e = 0; e < 8; ++e) { o0[e] = f2bf(acc[e]); o1[e] = f2bf(acc[8 + e]); }
                *(u16x8*)&h2[tile][lr][m * 128 + g * 16] = o0;
                *(u16x8*)&h2[tile][lr][m * 128 + g * 16 + 8] = o1;
            }
        }
    }
    __syncthreads();

    // ---- layer-2 GEMM (wave's 64-col half), split-K ----
    const int c = lane & 15, q = lane >> 4, koff = q * 8;
    u16* L = g2[tile];
    f32x4 acc[4] = {};
    const u16* Lr = &h2[tile][c][koff];
    const u16* hWT; const float *hB; float* outp;
    if (node) {
        hWT = A.fnWT; hB = A.fnb; outp = A.outn;
        const u16* Ap = A.Zb2n + (size_t)(m0 + c) * 384 + koff;
        const u16* Wp = A.nW1T + (size_t)(half * 64 + c) * 384 + koff;
        const size_t ws = (size_t)16 * 384;
#pragma unroll
        for (int k0 = 0; k0 < 256; k0 += 32) {
            bf16x8 af = *(const bf16x8*)(Ap + k0);
#pragma unroll
            for (int nt = 0; nt < 4; ++nt)
                acc[nt] = __builtin_amdgcn_mfma_f32_16x16x32_bf16(af, *(const bf16x8*)(Wp + nt * ws + k0), acc[nt], 0, 0, 0);
        }
#pragma unroll
        for (int k0 = 256; k0 < 384; k0 += 32) {
            bf16x8 af = *(const bf16x8*)(Lr + (k0 - 256));
#pragma unroll
            for (int nt = 0; nt < 4; ++nt)
                acc[nt] = __builtin_amdgcn_mfma_f32_16x16x32_bf16(af, *(const bf16x8*)(Wp + nt * ws + k0), acc[nt], 0, 0, 0);
        }
#pragma unroll
        for (int nt = 0; nt < 4; ++nt) {
            int col = half * 64 + nt * 16 + c;
            float bv = A.nb1s[col];
#pragma unroll
            for (int r = 0; r < 4; ++r)
                L[(q * 4 + r) * 128 + col] = f2bf(fmaxf(acc[nt][r] + bv, 0.f));
        }
    } else {
        hWT = A.feWT; hB = A.feb; outp = A.oute;
        const u16* Ap = A.Zb2e + (size_t)(m0 + c) * 640 + koff;
        const u16* Wp = A.eW2T + (size_t)(half * 64 + c) * 640 + koff;
        const size_t ws = (size_t)16 * 640;
#pragma unroll
        for (int k0 = 0; k0 < 256; k0 += 32) {
            bf16x8 af = *(const bf16x8*)(Ap + k0);
#pragma unroll
            for (int nt = 0; nt < 4; ++nt)
                acc[nt] = __builtin_amdgcn_mfma_f32_16x16x32_bf16(af, *(const bf16x8*)(Wp + nt * ws + k0), acc[nt], 0, 0, 0);
        }
#pragma unroll
        for (int k0 = 256; k0 < 384; k0 += 32) {
            bf16x8 af = *(const bf16x8*)(Lr + (k0 - 256));
#pragma unroll
            for (int nt = 0; nt < 4; ++nt)
                acc[nt] = __builtin_amdgcn_mfma_f32_16x16x32_bf16(af, *(const bf16x8*)(Wp + nt * ws + k0), acc[nt], 0, 0, 0);
        }
#pragma unroll
        for (int k0 = 384; k0 < 512; k0 += 32) {
            bf16x8 af = *(const bf16x8*)(Ap + k0);
#pragma unroll
            for (int nt = 0; nt < 4; ++nt)
                acc[nt] = __builtin_amdgcn_mfma_f32_16x16x32_bf16(af, *(const bf16x8*)(Wp + nt * ws + k0), acc[nt], 0, 0, 0);
        }
#pragma unroll
        for (int k0 = 512; k0 < 640; k0 += 32) {
            bf16x8 af = *(const bf16x8*)(Lr + (128 + k0 - 512));
#pragma unroll
            for (int nt = 0; nt < 4; ++nt)
                acc[nt] = __builtin_amdgcn_mfma_f32_16x16x32_bf16(af, *(const bf16x8*)(Wp + nt * ws + k0), acc[nt], 0, 0, 0);
        }
#pragma unroll
        for (int nt = 0; nt < 4; ++nt) {
            int col = half * 64 + nt * 16 + c;
            float bv = A.eb1[col];
#pragma unroll
            for (int r = 0; r < 4; ++r)
                L[(q * 4 + r) * 128 + col] = f2bf(fmaxf(acc[nt][r] + bv, 0.f));
        }
    }
    __syncthreads();

    // ---- head: this wave produces 32 of the 64 output cols of its tile ----
    f32x4 hacc[2] = {};
    const u16* Hp = hWT + (size_t)c * 128 + koff;
#pragma unroll
    for (int k0 = 0; k0 < 128; k0 += 32) {
        bf16x8 af = *(const bf16x8*)(L + c * 128 + koff + k0);
#pragma unroll
        for (int t2 = 0; t2 < 2; ++t2) {
            int nt = half * 2 + t2;
            bf16x8 bf = *(const bf16x8*)(Hp + nt * 16 * 128 + k0);
            hacc[t2] = __builtin_amdgcn_mfma_f32_16x16x32_bf16(af, bf, hacc[t2], 0, 0, 0);
        }
    }
#pragma unroll
    for (int t2 = 0; t2 < 2; ++t2) {
        int nt = half * 2 + t2;
        int col = nt * 16 + c;
        float bv = hB[col];
#pragma unroll
        for (int r = 0; r < 4; ++r)
            outp[(size_t)(m0 + q * 4 + r) * 64 + col] = hacc[t2][r] + bv;
    }
}

// ================= launch =================
extern "C" void kernel_launch(void* const* d_in, const int* in_sizes, int n_in,
                              void* d_out, int out_size, void* d_ws, size_t ws_size,
                              hipStream_t stream)
{
    const float* x    = (const float*)d_in[0];
    const float* ex   = (const float*)d_in[1];
    const int*   nei  = (const int*)d_in[2];
    const int*   eil  = (const int*)d_in[3];
    const float* eal  = (const float*)d_in[4];
    const int*   eiu  = (const int*)d_in[5];
    const float* eau  = (const float*)d_in[6];
    const float* nW0  = (const float*)d_in[7];
    const float* nb0  = (const float*)d_in[8];
    const float* nW1  = (const float*)d_in[9];
    const float* nb1  = (const float*)d_in[10];
    const float* fnW  = (const float*)d_in[11];
    const float* fnb  = (const float*)d_in[12];
    const float* eWl0 = (const float*)d_in[13];
    const float* eWu0 = (const float*)d_in[14];
    const float* eb0  = (const float*)d_in[15];
    const float* eWl1 = (const float*)d_in[16];
    const float* eWu1 = (const float*)d_in[17];
    const float* eb1  = (const float*)d_in[18];
    const float* feW  = (const float*)d_in[19];
    const float* feb  = (const float*)d_in[20];

    char* wsb = (char*)d_ws;
    size_t off = 0;
    auto alloc = [&](size_t bytes) { void* p = wsb + off; off += (bytes + 255) & ~(size_t)255; return p; };

    // ---- zeroed region (single small memset): raw append counters only ----
    u32* cntA = (u32*)alloc(NN * 4);
    u32* cntL = (u32*)alloc(NE * 4);
    u32* cntU = (u32*)alloc(NE * 4);
    size_t zbytes = off;   // ~82 KB

    uint2* rb1A = (uint2*)alloc((size_t)NN * CAP * 8);
    uint2* rb1L = (uint2*)alloc((size_t)NE * CAP * 8);
    uint2* rb1U = (uint2*)alloc((size_t)NE * CAP * 8);

    u32* colA = (u32*)alloc((size_t)NN * CAP * 4);
    u32* colL = (u32*)alloc((size_t)NE * CAP * 4);
    u32* colU = (u32*)alloc((size_t)NE * CAP * 4);
    u32* eidL = (u32*)alloc((size_t)NE * CAP * 4);
    u32* eidU = (u32*)alloc((size_t)NE * CAP * 4);

    u16* Zb1n = (u16*)alloc((size_t)4096 * 192 * 2);
    u16* Zb1e = (u16*)alloc((size_t)8192 * 160 * 2);
    u16* Zb2n = (u16*)alloc((size_t)4096 * 384 * 2);
    u16* Zb2e = (u16*)alloc((size_t)8192 * 640 * 2);

    u16* nW0T = (u16*)alloc((size_t)128 * 192 * 2);
    u16* nW1T = (u16*)alloc((size_t)128 * 384 * 2);
    u16* eW1T = (u16*)alloc((size_t)128 * 160 * 2);
    u16* eW2T = (u16*)alloc((size_t)128 * 640 * 2);
    u16* fnWT = (u16*)alloc((size_t)64 * 128 * 2);
    u16* feWT = (u16*)alloc((size_t)64 * 128 * 2);
    float* nb0s = (float*)alloc(128 * 4);
    float* nb1s = (float*)alloc(128 * 4);

    // ---- D0: zero counters (~82 KB) ----
    hipMemsetAsync(d_ws, 0, zbytes, stream);

    // ---- D1: prep + append ----
    PAArgs PA{x, ex, nW0, nW1, eWl0, eWu0, eWl1, eWu1, fnW, feW, nb0, nb1,
              nei, eil, eiu,
              cntA, cntL, cntU, colA, colL, colU, eidL, eidU,
              Zb1n, Zb1e, nW0T, nW1T, eW1T, eW2T, fnWT, feWT, nb0s, nb1s};
    prep_append<<<dim3(1024), dim3(256), 0, stream>>>(PA);

    // ---- D2: fused resolve + layer-1 hop-1 ----
    RHArgs RH{cntA, cntL, cntU, colA, colL, colU, eidL, eidU, eal, eau,
              rb1A, rb1L, rb1U, Zb1n, Zb1e};
    resolve_hop1<<<dim3(384), dim3(256), 0, stream>>>(RH);

    // ---- D3: layer-1 GEMMs with fused hop-2 ----
    {
        G1Args G1{Zb1n, Zb1e, nW0T, eW1T, nb0s, eb0,
                  cntA, cntL, cntU, rb1A, rb1L, rb1U, Zb2n, Zb2e};
        gemm1_kernel<<<dim3(192, 2), dim3(256), 0, stream>>>(G1);
    }

    // ---- D4: layer-2 hop-1 (width 8) ----
    {
        Seg3 P;
        P.s[0] = RSeg{cntA, rb1A, Zb2n, Zb2n + 128, NN << 4, 4, 384};
        P.s[1] = RSeg{cntL, rb1L, Zb2e, Zb2e + 128, NE << 4, 4, 640};
        P.s[2] = RSeg{cntU, rb1U, Zb2e, Zb2e + 384, NE << 4, 4, 640};
        int n = (NN << 4) + 2 * (NE << 4);
        spmm8_kernel<<<dim3((n + 255) / 256), dim3(256), 0, stream>>>(P);
    }

    // ---- D5: layer-2 GEMM + head with fused hop-2 ----
    {
        G2Args G2{Zb2n, Zb2e, nW1T, eW2T, fnWT, feWT,
                  nb1s, eb1, fnb, feb,
                  cntA, cntL, cntU, rb1A, rb1L, rb1U,
                  (float*)d_out, (float*)d_out + 262144};
        gemm2_head<<<dim3(384), dim3(256), 0, stream>>>(G2);
    }
}

// Round 7
// 166.180 us; speedup vs baseline: 3.3468x; 1.0134x over previous
//
#include <hip/hip_runtime.h>

#define NN 4096
#define NE 8192
#define NLG 32768
#define CAP 32

typedef unsigned int u32;
typedef unsigned short u16;
typedef __attribute__((ext_vector_type(4))) float f32x4;
typedef __attribute__((ext_vector_type(8))) short bf16x8;
typedef __attribute__((ext_vector_type(8))) unsigned short u16x8;
typedef __attribute__((ext_vector_type(4))) unsigned short u16x4;

__device__ __forceinline__ float bf2f(u16 u) { return __uint_as_float(((u32)u) << 16); }
__device__ __forceinline__ u16 f2bf(float f) {
    u32 x = __float_as_uint(f);
    return (u16)((x + 0x7fffu + ((x >> 16) & 1u)) >> 16);  // RNE
}

// ================= K1: prep (converts/transposes/bias) + bucket append, fused =================
struct PAArgs {
    const float *x, *ex;
    const float *nW0, *nW1, *eWl0, *eWu0, *eWl1, *eWu1, *fnW, *feW, *nb0, *nb1;
    const int *nei, *eil, *eiu;
    u32 *cntA, *cntL, *cntU;            // raw counters (zeroed by memset)
    u32 *colA, *colL, *colU, *eidL, *eidU;
    u16 *Zb1n, *Zb1e, *nW0T, *nW1T, *eW1T, *eW2T, *fnWT, *feWT;
    float *nb0s, *nb1s;
};

__device__ __forceinline__ void wtrK(const float* src, u16* dst, u32 i, int Kp, int Nw, int ld, int kofs) {
    int nn = i / Kp, kk = i - nn * Kp;
    dst[(size_t)nn * ld + kofs + kk] = f2bf(src[(size_t)kk * Nw + nn]);
}
__device__ __forceinline__ void wtrS(const float* sa, const float* sb, u16* dst, u32 i, int Kp, int Nw, int ld) {
    int nn = i / Kp, kk = i - nn * Kp;
    dst[(size_t)nn * ld + kk] = f2bf(sa[(size_t)kk * Nw + nn] + sb[(size_t)kk * Nw + nn]);
}

__global__ __launch_bounds__(256) void prep_append(PAArgs A) {
    const u32 gid = blockIdx.x * blockDim.x + threadIdx.x;
    const u32 gsz = gridDim.x * blockDim.x;
    const u32 C0 = 65536;                 // x conv (f32x4 units)
    const u32 C1 = C0 + 65536;            // ex conv
    const u32 C2 = C1 + 24576;            // nW0T (Kp=192)
    const u32 C3 = C2 + 49152;            // nW1T (Kp=384)
    const u32 C4 = C3 + 4096;             // eW1T sum block (Kp=32)
    const u32 C5 = C4 + 4096;             // eWl0 k=1
    const u32 C6 = C5 + 4096;             // eWl0 k=2
    const u32 C7 = C6 + 4096;             // eWu0 k=1
    const u32 C8 = C7 + 4096;             // eWu0 k=2
    const u32 C9 = C8 + 16384;            // eW2T sum block (Kp=128)
    const u32 C10 = C9 + 16384;           // eWl1 k=1
    const u32 C11 = C10 + 16384;          // eWl1 k=2
    const u32 C12 = C11 + 16384;          // eWu1 k=1
    const u32 C13 = C12 + 16384;          // eWu1 k=2
    const u32 C14 = C13 + 8192;           // fnWT
    const u32 C15 = C14 + 8192;           // feWT
    const u32 C16 = C15 + 256;            // bias sums
    const u32 C17 = C16 + (NE + 2 * NLG); // append
    for (u32 i = gid; i < C17; i += gsz) {
        if (i < C0) {
            u32 t = i; int r = t >> 4, c4 = t & 15;
            f32x4 v = *(const f32x4*)(A.x + (size_t)t * 4);
            u16x4 o;
#pragma unroll
            for (int e = 0; e < 4; ++e) o[e] = f2bf(v[e]);
            *(u16x4*)(A.Zb1n + (size_t)r * 192 + c4 * 4) = o;
        } else if (i < C1) {
            u32 t = i - C0; int r = t >> 3, c4 = t & 7;
            f32x4 v = *(const f32x4*)(A.ex + (size_t)t * 4);
            u16x4 o;
#pragma unroll
            for (int e = 0; e < 4; ++e) o[e] = f2bf(v[e]);
            *(u16x4*)(A.Zb1e + (size_t)r * 160 + c4 * 4) = o;
        }
        else if (i < C2)  wtrK(A.nW0, A.nW0T, i - C1, 192, 128, 192, 0);
        else if (i < C3)  wtrK(A.nW1, A.nW1T, i - C2, 384, 128, 384, 0);
        else if (i < C4)  wtrS(A.eWl0, A.eWu0, A.eW1T, i - C3, 32, 128, 160);
        else if (i < C5)  wtrK(A.eWl0 + 32 * 128,     A.eW1T, i - C4, 32, 128, 160, 32);
        else if (i < C6)  wtrK(A.eWl0 + 2 * 32 * 128, A.eW1T, i - C5, 32, 128, 160, 64);
        else if (i < C7)  wtrK(A.eWu0 + 32 * 128,     A.eW1T, i - C6, 32, 128, 160, 96);
        else if (i < C8)  wtrK(A.eWu0 + 2 * 32 * 128, A.eW1T, i - C7, 32, 128, 160, 128);
        else if (i < C9)  wtrS(A.eWl1, A.eWu1, A.eW2T, i - C8, 128, 128, 640);
        else if (i < C10) wtrK(A.eWl1 + 128 * 128,     A.eW2T, i - C9, 128, 128, 640, 128);
        else if (i < C11) wtrK(A.eWl1 + 2 * 128 * 128, A.eW2T, i - C10, 128, 128, 640, 256);
        else if (i < C12) wtrK(A.eWu1 + 128 * 128,     A.eW2T, i - C11, 128, 128, 640, 384);
        else if (i < C13) wtrK(A.eWu1 + 2 * 128 * 128, A.eW2T, i - C12, 128, 128, 640, 512);
        else if (i < C14) wtrK(A.fnW, A.fnWT, i - C13, 128, 64, 128, 0);
        else if (i < C15) wtrK(A.feW, A.feWT, i - C14, 128, 64, 128, 0);
        else if (i < C16) {
            u32 t = i - C15;
            if (t < 128) { float s = 0.f; for (int k = 0; k < 3; ++k) s += A.nb0[k * 128 + t]; A.nb0s[t] = s; }
            else { t -= 128; float s = 0.f; for (int k = 0; k < 3; ++k) s += A.nb1[k * 128 + t]; A.nb1s[t] = s; }
        } else {
            u32 t = i - C16;
            if (t < NE) {
                int r = A.nei[t];
                u32 p = atomicAdd(&A.cntA[r], 1u);
                if (p < CAP) A.colA[r * CAP + p] = (u32)A.nei[NE + t];
            } else if (t < NE + NLG) {
                u32 e = t - NE;
                int r = A.eil[e];
                u32 p = atomicAdd(&A.cntL[r], 1u);
                if (p < CAP) { A.colL[r * CAP + p] = (u32)A.eil[NLG + e]; A.eidL[r * CAP + p] = e; }
            } else {
                u32 e = t - NE - NLG;
                int r = A.eiu[e];
                u32 p = atomicAdd(&A.cntU[r], 1u);
                if (p < CAP) { A.colU[r * CAP + p] = (u32)A.eiu[NLG + e]; A.eidU[r * CAP + p] = e; }
            }
        }
    }
}

// ================= K2: fused resolve + layer-1 hop-1 spmm =================
// In-place semantics: loser/dup slots get w=0. A: first-slot-wins. L/U: max-eid-wins.
struct RHArgs {
    const u32 *cntA, *cntL, *cntU;
    const u32 *colA, *colL, *colU, *eidL, *eidU;
    const float *eal, *eau;
    uint2 *rb1A, *rb1L, *rb1U;
    u16 *Zb1n, *Zb1e;
};

__global__ __launch_bounds__(256) void resolve_hop1(RHArgs A) {
    __shared__ uint2 bkt[64][33];   // +1 pad: breaks 256B-stride bank aliasing
    __shared__ u32 jns[64];
    const int b = blockIdx.x, tid = threadIdx.x;
    const int seg = (b < 128) ? 0 : (b < 256 ? 1 : 2);   // A / L / U
    const int rowbase = (seg == 0 ? b : (seg == 1 ? b - 128 : b - 256)) * (seg == 0 ? 32 : 64);
    const u32* cnt = seg == 0 ? A.cntA : (seg == 1 ? A.cntL : A.cntU);
    const u32* col = seg == 0 ? A.colA : (seg == 1 ? A.colL : A.colU);
    uint2* rb = seg == 0 ? A.rb1A : (seg == 1 ? A.rb1L : A.rb1U);

    // ---- phase A: resolve into LDS + global rb1 ----
    {
        int lr, s, STR;
        if (seg == 0) { lr = tid >> 3; s = tid & 7; STR = 8; }   // 32 rows x 8 slot-threads
        else          { lr = tid >> 2; s = tid & 3; STR = 4; }   // 64 rows x 4 slot-threads
        int row = rowbase + lr;
        u32 jn = cnt[row]; if (jn > CAP) jn = CAP;
        if (s == 0) jns[lr] = jn;
        const u32* cp = col + row * CAP;
        if (seg == 0) {
            for (u32 j = s; j < jn; j += STR) {
                u32 cj = cp[j];
                float w = 1.0f;
                for (u32 j2 = 0; j2 < j; ++j2) if (cp[j2] == cj) { w = 0.0f; break; }
                uint2 v = make_uint2(cj, __float_as_uint(w));
                bkt[lr][j] = v; rb[row * CAP + j] = v;
            }
        } else {
            const u32* ep = (seg == 1 ? A.eidL : A.eidU) + row * CAP;
            const float* wsr = seg == 1 ? A.eal : A.eau;
            for (u32 j = s; j < jn; j += STR) {
                u32 cj = cp[j], ej = ep[j];
                float w = wsr[ej];
                for (u32 j2 = 0; j2 < jn; ++j2)
                    if (j2 != j && cp[j2] == cj && ep[j2] > ej) { w = 0.0f; break; }
                uint2 v = make_uint2(cj, __float_as_uint(w));
                bkt[lr][j] = v; rb[row * CAP + j] = v;
            }
        }
    }
    __syncthreads();

    // ---- phase B: hop-1 gather (width 8) using LDS buckets ----
    int lr2, g;
    if (seg == 0) { lr2 = tid >> 3; g = tid & 7; }   // 32 rows x 8 groups (64 cols)
    else          { lr2 = tid >> 2; g = tid & 3; }   // 64 rows x 4 groups (32 cols)
    const int row2 = rowbase + lr2;
    const u16* src = seg == 0 ? A.Zb1n : A.Zb1e;
    u16* dst = seg == 0 ? A.Zb1n + 64 : (seg == 1 ? A.Zb1e + 32 : A.Zb1e + 96);
    const int ld = seg == 0 ? 192 : 160;
    const u32 jn2 = jns[lr2];
    const u16* srcg = src + g * 8;
    float acc[8] = {};
    for (u32 j = 0; j < jn2; ++j) {
        uint2 q = bkt[lr2][j];
        u16x8 xv = *(const u16x8*)(srcg + (size_t)q.x * ld);
        float w = __uint_as_float(q.y);
#pragma unroll
        for (int e = 0; e < 8; ++e) acc[e] = fmaf(w, bf2f(xv[e]), acc[e]);
    }
    u16x8 o;
#pragma unroll
    for (int e = 0; e < 8; ++e) o[e] = f2bf(acc[e]);
    *(u16x8*)(dst + (size_t)row2 * ld + g * 8) = o;
}

// ================= layer-2 hop-1 spmm: 8 threads/row, dual 8-col slices =================
struct RSeg { const u32* cnt; const uint2* rb; const u16* src; u16* dst; int n; int ld; };
struct Seg3 { RSeg s[3]; };

__device__ __forceinline__ void spmm_row16(const RSeg& s, int t) {
    int row = t >> 3, g = t & 7;
    u32 jn = s.cnt[row]; if (jn > CAP) jn = CAP;
    const uint2* bp = s.rb + (size_t)row * CAP;
    const u16* s0 = s.src + g * 8;
    const u16* s1 = s.src + g * 8 + 64;
    float acc[16] = {};
    u32 j = 0;
    for (; j + 2 <= jn; j += 2) {
        uint2 q0 = bp[j], q1 = bp[j + 1];
        u16x8 a0 = *(const u16x8*)(s0 + (size_t)q0.x * s.ld);
        u16x8 b0 = *(const u16x8*)(s1 + (size_t)q0.x * s.ld);
        u16x8 a1 = *(const u16x8*)(s0 + (size_t)q1.x * s.ld);
        u16x8 b1 = *(const u16x8*)(s1 + (size_t)q1.x * s.ld);
        float w0 = __uint_as_float(q0.y), w1 = __uint_as_float(q1.y);
#pragma unroll
        for (int e = 0; e < 8; ++e) {
            acc[e]     = fmaf(w0, bf2f(a0[e]), acc[e]);
            acc[8 + e] = fmaf(w0, bf2f(b0[e]), acc[8 + e]);
            acc[e]     = fmaf(w1, bf2f(a1[e]), acc[e]);
            acc[8 + e] = fmaf(w1, bf2f(b1[e]), acc[8 + e]);
        }
    }
    for (; j < jn; ++j) {
        uint2 q = bp[j];
        u16x8 a0 = *(const u16x8*)(s0 + (size_t)q.x * s.ld);
        u16x8 b0 = *(const u16x8*)(s1 + (size_t)q.x * s.ld);
        float w = __uint_as_float(q.y);
#pragma unroll
        for (int e = 0; e < 8; ++e) {
            acc[e]     = fmaf(w, bf2f(a0[e]), acc[e]);
            acc[8 + e] = fmaf(w, bf2f(b0[e]), acc[8 + e]);
        }
    }
    u16x8 o0, o1;
#pragma unroll
    for (int e = 0; e < 8; ++e) { o0[e] = f2bf(acc[e]); o1[e] = f2bf(acc[8 + e]); }
    *(u16x8*)(s.dst + (size_t)row * s.ld + g * 8) = o0;
    *(u16x8*)(s.dst + (size_t)row * s.ld + g * 8 + 64) = o1;
}

__global__ __launch_bounds__(256) void spmm16_kernel(Seg3 P) {
    int id = blockIdx.x * blockDim.x + threadIdx.x;
    int base = 0;
#pragma unroll
    for (int i = 0; i < 3; ++i) {
        int n = P.s[i].n;
        if (id < base + n) { spmm_row16(P.s[i], id - base); return; }
        base += n;
    }
}

// ================= K4: layer-1 GEMM with fused hop-2 =================
// 1 tile/block (grid 768), 2 waves. 128 threads stage the tile's hop-2 into LDS
// once, then wave wv computes its 64-col N-half.
// node A-tile: k[0,128) global (x|hop1), k[128,192) LDS (hop2)
// edge A-tile: k[0,64) g, k[64,96) LDS(L2), k[96,128) g, k[128,160) LDS(U2)
struct G1Args {
    const u16 *Zb1n, *Zb1e, *nW0T, *eW1T;
    const float *nb0s, *eb0;
    const u32 *cntA, *cntL, *cntU;
    const uint2 *rb1A, *rb1L, *rb1U;
    u16 *Zb2n, *Zb2e;
};

__global__ __launch_bounds__(128) void gemm1_kernel(G1Args A) {
    __shared__ u16 h2[16][72];   // stride 72: fragment reads land 2-way (free)
    const int tid = threadIdx.x;
    const int half = tid >> 6, lane = tid & 63;
    const int s = blockIdx.x;               // 0..767 tiles (256 node + 512 edge)
    const bool node = s < 256;
    const int m0 = (node ? s : s - 256) * 16;

    // ---- stage hop2 (all 128 threads, once per tile; 8 thr/row) ----
    // node: 64 cols (8 slices). edge: L2 32 cols (g 0..3), U2 32 cols (g 4..7).
    {
        const int lr = tid >> 3, g = tid & 7;
        const u32* cnt; const uint2* rb; const u16* src; int ld, dc;
        if (node) { cnt = A.cntA; rb = A.rb1A; src = A.Zb1n + 64 + g * 8; ld = 192; dc = g * 8; }
        else {
            const bool isL = g < 4; const int gg = isL ? g : g - 4;
            cnt = isL ? A.cntL : A.cntU; rb = isL ? A.rb1L : A.rb1U;
            src = (isL ? A.Zb1e + 32 : A.Zb1e + 96) + gg * 8; ld = 160;
            dc = (isL ? 0 : 32) + gg * 8;
        }
        const int row = m0 + lr;
        u32 jn = cnt[row]; if (jn > CAP) jn = CAP;
        const uint2* bp = rb + (size_t)row * CAP;
        float acc[8] = {};
        for (u32 j = 0; j < jn; ++j) {
            uint2 qe = bp[j];
            float w = __uint_as_float(qe.y);
            u16x8 a0 = *(const u16x8*)(src + (size_t)qe.x * ld);
#pragma unroll
            for (int e = 0; e < 8; ++e) acc[e] = fmaf(w, bf2f(a0[e]), acc[e]);
        }
        u16x8 o0;
#pragma unroll
        for (int e = 0; e < 8; ++e) o0[e] = f2bf(acc[e]);
        *(u16x8*)&h2[lr][dc] = o0;
    }
    __syncthreads();

    // ---- MFMA GEMM, split-K; wave = one 64-col N-half ----
    const int row = lane & 15, koff = (lane >> 4) * 8;
    const int n0 = half * 64;
    f32x4 acc[4] = {};
    const u16* Lr = &h2[row][koff];
    if (node) {
        const u16* Ap = A.Zb1n + (size_t)(m0 + row) * 192 + koff;
        const u16* Wp = A.nW0T + (size_t)(n0 + row) * 192 + koff;
        const size_t ws = (size_t)16 * 192;
#pragma unroll
        for (int k0 = 0; k0 < 128; k0 += 32) {
            bf16x8 af = *(const bf16x8*)(Ap + k0);
#pragma unroll
            for (int nt = 0; nt < 4; ++nt)
                acc[nt] = __builtin_amdgcn_mfma_f32_16x16x32_bf16(af, *(const bf16x8*)(Wp + nt * ws + k0), acc[nt], 0, 0, 0);
        }
#pragma unroll
        for (int k0 = 128; k0 < 192; k0 += 32) {
            bf16x8 af = *(const bf16x8*)(Lr + (k0 - 128));
#pragma unroll
            for (int nt = 0; nt < 4; ++nt)
                acc[nt] = __builtin_amdgcn_mfma_f32_16x16x32_bf16(af, *(const bf16x8*)(Wp + nt * ws + k0), acc[nt], 0, 0, 0);
        }
        const int orow = m0 + (lane >> 4) * 4;
#pragma unroll
        for (int nt = 0; nt < 4; ++nt) {
            int col = n0 + nt * 16 + row;
            float bv = A.nb0s[col];
#pragma unroll
            for (int r = 0; r < 4; ++r)
                A.Zb2n[(size_t)(orow + r) * 384 + col] = f2bf(fmaxf(acc[nt][r] + bv, 0.f));
        }
    } else {
        const u16* Ap = A.Zb1e + (size_t)(m0 + row) * 160 + koff;
        const u16* Wp = A.eW1T + (size_t)(n0 + row) * 160 + koff;
        const size_t ws = (size_t)16 * 160;
        bf16x8 af;
        af = *(const bf16x8*)(Ap + 0);
#pragma unroll
        for (int nt = 0; nt < 4; ++nt)
            acc[nt] = __builtin_amdgcn_mfma_f32_16x16x32_bf16(af, *(const bf16x8*)(Wp + nt * ws + 0), acc[nt], 0, 0, 0);
        af = *(const bf16x8*)(Ap + 32);
#pragma unroll
        for (int nt = 0; nt < 4; ++nt)
            acc[nt] = __builtin_amdgcn_mfma_f32_16x16x32_bf16(af, *(const bf16x8*)(Wp + nt * ws + 32), acc[nt], 0, 0, 0);
        af = *(const bf16x8*)(Lr + 0);      // L2 hop2, kabs 64
#pragma unroll
        for (int nt = 0; nt < 4; ++nt)
            acc[nt] = __builtin_amdgcn_mfma_f32_16x16x32_bf16(af, *(const bf16x8*)(Wp + nt * ws + 64), acc[nt], 0, 0, 0);
        af = *(const bf16x8*)(Ap + 96);
#pragma unroll
        for (int nt = 0; nt < 4; ++nt)
            acc[nt] = __builtin_amdgcn_mfma_f32_16x16x32_bf16(af, *(const bf16x8*)(Wp + nt * ws + 96), acc[nt], 0, 0, 0);
        af = *(const bf16x8*)(Lr + 32);     // U2 hop2, kabs 128
#pragma unroll
        for (int nt = 0; nt < 4; ++nt)
            acc[nt] = __builtin_amdgcn_mfma_f32_16x16x32_bf16(af, *(const bf16x8*)(Wp + nt * ws + 128), acc[nt], 0, 0, 0);
        const int orow = m0 + (lane >> 4) * 4;
#pragma unroll
        for (int nt = 0; nt < 4; ++nt) {
            int col = n0 + nt * 16 + row;
            float bv = A.eb0[col];
#pragma unroll
            for (int r = 0; r < 4; ++r)
                A.Zb2e[(size_t)(orow + r) * 640 + col] = f2bf(fmaxf(acc[nt][r] + bv, 0.f));
        }
    }
}

// ================= K6: layer-2 GEMM + head with fused hop-2 =================
// 1 tile/block (grid 768, 3 blocks/CU), 4 waves. 256 threads stage hop-2 (16 thr/row;
// edge threads loop L2+U2 for full 256-col coverage); GEMM N-split 4x32 cols/wave;
// head N-split 4x16 cols/wave. Split-K:
// node: k[0,256) global (h|hop1), k[256,384) LDS
// edge: k[0,256) g, k[256,384) LDS(L2), k[384,512) g, k[512,640) LDS(U2)
struct G2Args {
    const u16 *Zb2n, *Zb2e, *nW1T, *eW2T, *fnWT, *feWT;
    const float *nb1s, *eb1, *fnb, *feb;
    const u32 *cntA, *cntL, *cntU;
    const uint2 *rb1A, *rb1L, *rb1U;
    float *outn, *oute;
};

__global__ __launch_bounds__(256) void gemm2_head(G2Args A) {
    __shared__ u16 h2[16][264];   // stride 264: fragment reads land 2-way
    __shared__ u16 g2[16 * 128];
    const int tid = threadIdx.x;
    const int wv = tid >> 6, lane = tid & 63;
    const int s = blockIdx.x;               // 0..767 tiles
    const bool node = s < 256;
    const int m0 = (node ? s : s - 256) * 16;

    // ---- stage hop2 (all 256 threads, 16 thr/row) ----
    {
        const int lr = tid >> 4, g = tid & 15;
        const int row = m0 + lr;
        if (node) {
            // 128 cols: slice g of 8
            u32 jn = A.cntA[row]; if (jn > CAP) jn = CAP;
            const uint2* bp = A.rb1A + (size_t)row * CAP;
            const u16* src = A.Zb2n + 128 + g * 8;
            float acc[8] = {};
            for (u32 j = 0; j < jn; ++j) {
                uint2 qe = bp[j];
                float w = __uint_as_float(qe.y);
                u16x8 a0 = *(const u16x8*)(src + (size_t)qe.x * 384);
#pragma unroll
                for (int e = 0; e < 8; ++e) acc[e] = fmaf(w, bf2f(a0[e]), acc[e]);
            }
            u16x8 o0;
#pragma unroll
            for (int e = 0; e < 8; ++e) o0[e] = f2bf(acc[e]);
            *(u16x8*)&h2[lr][g * 8] = o0;
        } else {
            // 256 cols: each thread does slice g of L2 (dc g*8) AND of U2 (dc 128+g*8)
#pragma unroll
            for (int m = 0; m < 2; ++m) {
                const u32* cnt = m == 0 ? A.cntL : A.cntU;
                const uint2* rb = m == 0 ? A.rb1L : A.rb1U;
                const u16* src = (m == 0 ? A.Zb2e + 128 : A.Zb2e + 384) + g * 8;
                u32 jn = cnt[row]; if (jn > CAP) jn = CAP;
                const uint2* bp = rb + (size_t)row * CAP;
                float acc[8] = {};
                for (u32 j = 0; j < jn; ++j) {
                    uint2 qe = bp[j];
                    float w = __uint_as_float(qe.y);
                    u16x8 a0 = *(const u16x8*)(src + (size_t)qe.x * 640);
#pragma unroll
                    for (int e = 0; e < 8; ++e) acc[e] = fmaf(w, bf2f(a0[e]), acc[e]);
                }
                u16x8 o0;
#pragma unroll
                for (int e = 0; e < 8; ++e) o0[e] = f2bf(acc[e]);
                *(u16x8*)&h2[lr][m * 128 + g * 8] = o0;
            }
        }
    }
    __syncthreads();

    // ---- layer-2 GEMM: wave wv computes 32 N-cols ----
    const int c = lane & 15, q = lane >> 4, koff = q * 8;
    f32x4 acc[2] = {};
    const u16* Lr = &h2[c][koff];
    const u16* hWT; const float *hB; float* outp;
    if (node) {
        hWT = A.fnWT; hB = A.fnb; outp = A.outn;
        const u16* Ap = A.Zb2n + (size_t)(m0 + c) * 384 + koff;
        const u16* Wp = A.nW1T + (size_t)(wv * 32 + c) * 384 + koff;
        const size_t ws = (size_t)16 * 384;
#pragma unroll
        for (int k0 = 0; k0 < 256; k0 += 32) {
            bf16x8 af = *(const bf16x8*)(Ap + k0);
#pragma unroll
            for (int nt = 0; nt < 2; ++nt)
                acc[nt] = __builtin_amdgcn_mfma_f32_16x16x32_bf16(af, *(const bf16x8*)(Wp + nt * ws + k0), acc[nt], 0, 0, 0);
        }
#pragma unroll
        for (int k0 = 256; k0 < 384; k0 += 32) {
            bf16x8 af = *(const bf16x8*)(Lr + (k0 - 256));
#pragma unroll
            for (int nt = 0; nt < 2; ++nt)
                acc[nt] = __builtin_amdgcn_mfma_f32_16x16x32_bf16(af, *(const bf16x8*)(Wp + nt * ws + k0), acc[nt], 0, 0, 0);
        }
#pragma unroll
        for (int nt = 0; nt < 2; ++nt) {
            int col = wv * 32 + nt * 16 + c;
            float bv = A.nb1s[col];
#pragma unroll
            for (int r = 0; r < 4; ++r)
                g2[(q * 4 + r) * 128 + col] = f2bf(fmaxf(acc[nt][r] + bv, 0.f));
        }
    } else {
        hWT = A.feWT; hB = A.feb; outp = A.oute;
        const u16* Ap = A.Zb2e + (size_t)(m0 + c) * 640 + koff;
        const u16* Wp = A.eW2T + (size_t)(wv * 32 + c) * 640 + koff;
        const size_t ws = (size_t)16 * 640;
#pragma unroll
        for (int k0 = 0; k0 < 256; k0 += 32) {
            bf16x8 af = *(const bf16x8*)(Ap + k0);
#pragma unroll
            for (int nt = 0; nt < 2; ++nt)
                acc[nt] = __builtin_amdgcn_mfma_f32_16x16x32_bf16(af, *(const bf16x8*)(Wp + nt * ws + k0), acc[nt], 0, 0, 0);
        }
#pragma unroll
        for (int k0 = 256; k0 < 384; k0 += 32) {
            bf16x8 af = *(const bf16x8*)(Lr + (k0 - 256));
#pragma unroll
            for (int nt = 0; nt < 2; ++nt)
                acc[nt] = __builtin_amdgcn_mfma_f32_16x16x32_bf16(af, *(const bf16x8*)(Wp + nt * ws + k0), acc[nt], 0, 0, 0);
        }
#pragma unroll
        for (int k0 = 384; k0 < 512; k0 += 32) {
            bf16x8 af = *(const bf16x8*)(Ap + k0);
#pragma unroll
            for (int nt = 0; nt < 2; ++nt)
                acc[nt] = __builtin_amdgcn_mfma_f32_16x16x32_bf16(af, *(const bf16x8*)(Wp + nt * ws + k0), acc[nt], 0, 0, 0);
        }
#pragma unroll
        for (int k0 = 512; k0 < 640; k0 += 32) {
            bf16x8 af = *(const bf16x8*)(Lr + (128 + k0 - 512));
#pragma unroll
            for (int nt = 0; nt < 2; ++nt)
                acc[nt] = __builtin_amdgcn_mfma_f32_16x16x32_bf16(af, *(const bf16x8*)(Wp + nt * ws + k0), acc[nt], 0, 0, 0);
        }
#pragma unroll
        for (int nt = 0; nt < 2; ++nt) {
            int col = wv * 32 + nt * 16 + c;
            float bv = A.eb1[col];
#pragma unroll
            for (int r = 0; r < 4; ++r)
                g2[(q * 4 + r) * 128 + col] = f2bf(fmaxf(acc[nt][r] + bv, 0.f));
        }
    }
    __syncthreads();

    // ---- head: wave wv produces 16 of the 64 output cols ----
    f32x4 hacc = {};
    const u16* Hp = hWT + (size_t)(wv * 16 + c) * 128 + koff;
#pragma unroll
    for (int k0 = 0; k0 < 128; k0 += 32) {
        bf16x8 af = *(const bf16x8*)(g2 + c * 128 + koff + k0);
        bf16x8 bf = *(const bf16x8*)(Hp + k0);
        hacc = __builtin_amdgcn_mfma_f32_16x16x32_bf16(af, bf, hacc, 0, 0, 0);
    }
    {
        int col = wv * 16 + c;
        float bv = hB[col];
#pragma unroll
        for (int r = 0; r < 4; ++r)
            outp[(size_t)(m0 + q * 4 + r) * 64 + col] = hacc[r] + bv;
    }
}

// ================= launch =================
extern "C" void kernel_launch(void* const* d_in, const int* in_sizes, int n_in,
                              void* d_out, int out_size, void* d_ws, size_t ws_size,
                              hipStream_t stream)
{
    const float* x    = (const float*)d_in[0];
    const float* ex   = (const float*)d_in[1];
    const int*   nei  = (const int*)d_in[2];
    const int*   eil  = (const int*)d_in[3];
    const float* eal  = (const float*)d_in[4];
    const int*   eiu  = (const int*)d_in[5];
    const float* eau  = (const float*)d_in[6];
    const float* nW0  = (const float*)d_in[7];
    const float* nb0  = (const float*)d_in[8];
    const float* nW1  = (const float*)d_in[9];
    const float* nb1  = (const float*)d_in[10];
    const float* fnW  = (const float*)d_in[11];
    const float* fnb  = (const float*)d_in[12];
    const float* eWl0 = (const float*)d_in[13];
    const float* eWu0 = (const float*)d_in[14];
    const float* eb0  = (const float*)d_in[15];
    const float* eWl1 = (const float*)d_in[16];
    const float* eWu1 = (const float*)d_in[17];
    const float* eb1  = (const float*)d_in[18];
    const float* feW  = (const float*)d_in[19];
    const float* feb  = (const float*)d_in[20];

    char* wsb = (char*)d_ws;
    size_t off = 0;
    auto alloc = [&](size_t bytes) { void* p = wsb + off; off += (bytes + 255) & ~(size_t)255; return p; };

    // ---- zeroed region (single small memset): raw append counters only ----
    u32* cntA = (u32*)alloc(NN * 4);
    u32* cntL = (u32*)alloc(NE * 4);
    u32* cntU = (u32*)alloc(NE * 4);
    size_t zbytes = off;   // ~82 KB

    uint2* rb1A = (uint2*)alloc((size_t)NN * CAP * 8);
    uint2* rb1L = (uint2*)alloc((size_t)NE * CAP * 8);
    uint2* rb1U = (uint2*)alloc((size_t)NE * CAP * 8);

    u32* colA = (u32*)alloc((size_t)NN * CAP * 4);
    u32* colL = (u32*)alloc((size_t)NE * CAP * 4);
    u32* colU = (u32*)alloc((size_t)NE * CAP * 4);
    u32* eidL = (u32*)alloc((size_t)NE * CAP * 4);
    u32* eidU = (u32*)alloc((size_t)NE * CAP * 4);

    u16* Zb1n = (u16*)alloc((size_t)4096 * 192 * 2);
    u16* Zb1e = (u16*)alloc((size_t)8192 * 160 * 2);
    u16* Zb2n = (u16*)alloc((size_t)4096 * 384 * 2);
    u16* Zb2e = (u16*)alloc((size_t)8192 * 640 * 2);

    u16* nW0T = (u16*)alloc((size_t)128 * 192 * 2);
    u16* nW1T = (u16*)alloc((size_t)128 * 384 * 2);
    u16* eW1T = (u16*)alloc((size_t)128 * 160 * 2);
    u16* eW2T = (u16*)alloc((size_t)128 * 640 * 2);
    u16* fnWT = (u16*)alloc((size_t)64 * 128 * 2);
    u16* feWT = (u16*)alloc((size_t)64 * 128 * 2);
    float* nb0s = (float*)alloc(128 * 4);
    float* nb1s = (float*)alloc(128 * 4);

    // ---- D0: zero counters (~82 KB) ----
    hipMemsetAsync(d_ws, 0, zbytes, stream);

    // ---- D1: prep + append ----
    PAArgs PA{x, ex, nW0, nW1, eWl0, eWu0, eWl1, eWu1, fnW, feW, nb0, nb1,
              nei, eil, eiu,
              cntA, cntL, cntU, colA, colL, colU, eidL, eidU,
              Zb1n, Zb1e, nW0T, nW1T, eW1T, eW2T, fnWT, feWT, nb0s, nb1s};
    prep_append<<<dim3(1024), dim3(256), 0, stream>>>(PA);

    // ---- D2: fused resolve + layer-1 hop-1 ----
    RHArgs RH{cntA, cntL, cntU, colA, colL, colU, eidL, eidU, eal, eau,
              rb1A, rb1L, rb1U, Zb1n, Zb1e};
    resolve_hop1<<<dim3(384), dim3(256), 0, stream>>>(RH);

    // ---- D3: layer-1 GEMMs with fused hop-2 (1 tile/block, 2 waves) ----
    {
        G1Args G1{Zb1n, Zb1e, nW0T, eW1T, nb0s, eb0,
                  cntA, cntL, cntU, rb1A, rb1L, rb1U, Zb2n, Zb2e};
        gemm1_kernel<<<dim3(768), dim3(128), 0, stream>>>(G1);
    }

    // ---- D4: layer-2 hop-1 (8 thr/row, dual slices) ----
    {
        Seg3 P;
        P.s[0] = RSeg{cntA, rb1A, Zb2n, Zb2n + 128, NN << 3, 384};
        P.s[1] = RSeg{cntL, rb1L, Zb2e, Zb2e + 128, NE << 3, 640};
        P.s[2] = RSeg{cntU, rb1U, Zb2e, Zb2e + 384, NE << 3, 640};
        int n = (NN << 3) + 2 * (NE << 3);
        spmm16_kernel<<<dim3((n + 255) / 256), dim3(256), 0, stream>>>(P);
    }

    // ---- D5: layer-2 GEMM + head with fused hop-2 (1 tile/block, 4 waves) ----
    {
        G2Args G2{Zb2n, Zb2e, nW1T, eW2T, fnWT, feWT,
                  nb1s, eb1, fnb, feb,
                  cntA, cntL, cntU, rb1A, rb1L, rb1U,
                  (float*)d_out, (float*)d_out + 262144};
        gemm2_head<<<dim3(768), dim3(256), 0, stream>>>(G2);
    }
}

// Round 8
// 162.080 us; speedup vs baseline: 3.4315x; 1.0253x over previous
//
#include <hip/hip_runtime.h>

#define NN 4096
#define NE 8192
#define NLG 32768
#define CAP 32

typedef unsigned int u32;
typedef unsigned short u16;
typedef __attribute__((ext_vector_type(4))) float f32x4;
typedef __attribute__((ext_vector_type(8))) short bf16x8;
typedef __attribute__((ext_vector_type(8))) unsigned short u16x8;
typedef __attribute__((ext_vector_type(4))) unsigned short u16x4;

__device__ __forceinline__ float bf2f(u16 u) { return __uint_as_float(((u32)u) << 16); }
__device__ __forceinline__ u16 f2bf(float f) {
    u32 x = __float_as_uint(f);
    return (u16)((x + 0x7fffu + ((x >> 16) & 1u)) >> 16);  // RNE
}

// ================= K1: prep (converts/transposes/bias) + bucket append, fused =================
struct PAArgs {
    const float *x, *ex;
    const float *nW0, *nW1, *eWl0, *eWu0, *eWl1, *eWu1, *fnW, *feW, *nb0, *nb1;
    const int *nei, *eil, *eiu;
    u32 *cntA, *cntL, *cntU;            // raw counters (zeroed by memset)
    u32 *colA, *colL, *colU, *eidL, *eidU;
    u16 *Zb1n, *Zb1e, *nW0T, *nW1T, *eW1T, *eW2T, *fnWT, *feWT;
    float *nb0s, *nb1s;
};

// 4-wide transpose: thread reads 16B coalesced (4 consecutive nn of src row kk),
// writes 4 elems down dst's contiguous-fast kk dim (L2-absorbed scatter).
__device__ __forceinline__ void wtrK4(const float* src, u16* dst, u32 i, int Kp, int Nw, int ld, int kofs) {
    int n4 = i / Kp, kk = i - n4 * Kp, nn = n4 * 4;
    f32x4 v = *(const f32x4*)(src + (size_t)kk * Nw + nn);
#pragma unroll
    for (int e = 0; e < 4; ++e) dst[(size_t)(nn + e) * ld + kofs + kk] = f2bf(v[e]);
}
__device__ __forceinline__ void wtrS4(const float* sa, const float* sb, u16* dst, u32 i, int Kp, int Nw, int ld) {
    int n4 = i / Kp, kk = i - n4 * Kp, nn = n4 * 4;
    f32x4 va = *(const f32x4*)(sa + (size_t)kk * Nw + nn);
    f32x4 vb = *(const f32x4*)(sb + (size_t)kk * Nw + nn);
#pragma unroll
    for (int e = 0; e < 4; ++e) dst[(size_t)(nn + e) * ld + kk] = f2bf(va[e] + vb[e]);
}

__global__ __launch_bounds__(256) void prep_append(PAArgs A) {
    const u32 gid = blockIdx.x * blockDim.x + threadIdx.x;
    const u32 gsz = gridDim.x * blockDim.x;
    const u32 C0 = 65536;                 // x conv (f32x4 units)
    const u32 C1 = C0 + 65536;            // ex conv
    const u32 C2 = C1 + 6144;             // nW0T (Kp=192, /4)
    const u32 C3 = C2 + 12288;            // nW1T (Kp=384, /4)
    const u32 C4 = C3 + 1024;             // eW1T sum block (Kp=32, /4)
    const u32 C5 = C4 + 1024;             // eWl0 k=1
    const u32 C6 = C5 + 1024;             // eWl0 k=2
    const u32 C7 = C6 + 1024;             // eWu0 k=1
    const u32 C8 = C7 + 1024;             // eWu0 k=2
    const u32 C9 = C8 + 4096;             // eW2T sum block (Kp=128, /4)
    const u32 C10 = C9 + 4096;            // eWl1 k=1
    const u32 C11 = C10 + 4096;           // eWl1 k=2
    const u32 C12 = C11 + 4096;           // eWu1 k=1
    const u32 C13 = C12 + 4096;           // eWu1 k=2
    const u32 C14 = C13 + 2048;           // fnWT
    const u32 C15 = C14 + 2048;           // feWT
    const u32 C16 = C15 + 256;            // bias sums
    const u32 C17 = C16 + (NE + 2 * NLG); // append
    for (u32 i = gid; i < C17; i += gsz) {
        if (i < C0) {
            u32 t = i; int r = t >> 4, c4 = t & 15;
            f32x4 v = *(const f32x4*)(A.x + (size_t)t * 4);
            u16x4 o;
#pragma unroll
            for (int e = 0; e < 4; ++e) o[e] = f2bf(v[e]);
            *(u16x4*)(A.Zb1n + (size_t)r * 192 + c4 * 4) = o;
        } else if (i < C1) {
            u32 t = i - C0; int r = t >> 3, c4 = t & 7;
            f32x4 v = *(const f32x4*)(A.ex + (size_t)t * 4);
            u16x4 o;
#pragma unroll
            for (int e = 0; e < 4; ++e) o[e] = f2bf(v[e]);
            *(u16x4*)(A.Zb1e + (size_t)r * 160 + c4 * 4) = o;
        }
        else if (i < C2)  wtrK4(A.nW0, A.nW0T, i - C1, 192, 128, 192, 0);
        else if (i < C3)  wtrK4(A.nW1, A.nW1T, i - C2, 384, 128, 384, 0);
        else if (i < C4)  wtrS4(A.eWl0, A.eWu0, A.eW1T, i - C3, 32, 128, 160);
        else if (i < C5)  wtrK4(A.eWl0 + 32 * 128,     A.eW1T, i - C4, 32, 128, 160, 32);
        else if (i < C6)  wtrK4(A.eWl0 + 2 * 32 * 128, A.eW1T, i - C5, 32, 128, 160, 64);
        else if (i < C7)  wtrK4(A.eWu0 + 32 * 128,     A.eW1T, i - C6, 32, 128, 160, 96);
        else if (i < C8)  wtrK4(A.eWu0 + 2 * 32 * 128, A.eW1T, i - C7, 32, 128, 160, 128);
        else if (i < C9)  wtrS4(A.eWl1, A.eWu1, A.eW2T, i - C8, 128, 128, 640);
        else if (i < C10) wtrK4(A.eWl1 + 128 * 128,     A.eW2T, i - C9, 128, 128, 640, 128);
        else if (i < C11) wtrK4(A.eWl1 + 2 * 128 * 128, A.eW2T, i - C10, 128, 128, 640, 256);
        else if (i < C12) wtrK4(A.eWu1 + 128 * 128,     A.eW2T, i - C11, 128, 128, 640, 384);
        else if (i < C13) wtrK4(A.eWu1 + 2 * 128 * 128, A.eW2T, i - C12, 128, 128, 640, 512);
        else if (i < C14) wtrK4(A.fnW, A.fnWT, i - C13, 128, 64, 128, 0);
        else if (i < C15) wtrK4(A.feW, A.feWT, i - C14, 128, 64, 128, 0);
        else if (i < C16) {
            u32 t = i - C15;
            if (t < 128) { float s = 0.f; for (int k = 0; k < 3; ++k) s += A.nb0[k * 128 + t]; A.nb0s[t] = s; }
            else { t -= 128; float s = 0.f; for (int k = 0; k < 3; ++k) s += A.nb1[k * 128 + t]; A.nb1s[t] = s; }
        } else {
            u32 t = i - C16;
            if (t < NE) {
                int r = A.nei[t];
                u32 p = atomicAdd(&A.cntA[r], 1u);
                if (p < CAP) A.colA[r * CAP + p] = (u32)A.nei[NE + t];
            } else if (t < NE + NLG) {
                u32 e = t - NE;
                int r = A.eil[e];
                u32 p = atomicAdd(&A.cntL[r], 1u);
                if (p < CAP) { A.colL[r * CAP + p] = (u32)A.eil[NLG + e]; A.eidL[r * CAP + p] = e; }
            } else {
                u32 e = t - NE - NLG;
                int r = A.eiu[e];
                u32 p = atomicAdd(&A.cntU[r], 1u);
                if (p < CAP) { A.colU[r * CAP + p] = (u32)A.eiu[NLG + e]; A.eidU[r * CAP + p] = e; }
            }
        }
    }
}

// ================= K2: fused resolve + layer-1 hop-1 spmm =================
// In-place semantics: loser/dup slots get w=0. A: first-slot-wins. L/U: max-eid-wins.
struct RHArgs {
    const u32 *cntA, *cntL, *cntU;
    const u32 *colA, *colL, *colU, *eidL, *eidU;
    const float *eal, *eau;
    uint2 *rb1A, *rb1L, *rb1U;
    u16 *Zb1n, *Zb1e;
};

__global__ __launch_bounds__(256) void resolve_hop1(RHArgs A) {
    __shared__ uint2 bkt[64][33];   // +1 pad: breaks 256B-stride bank aliasing
    __shared__ u32 jns[64];
    const int b = blockIdx.x, tid = threadIdx.x;
    const int seg = (b < 128) ? 0 : (b < 256 ? 1 : 2);   // A / L / U
    const int rowbase = (seg == 0 ? b : (seg == 1 ? b - 128 : b - 256)) * (seg == 0 ? 32 : 64);
    const u32* cnt = seg == 0 ? A.cntA : (seg == 1 ? A.cntL : A.cntU);
    const u32* col = seg == 0 ? A.colA : (seg == 1 ? A.colL : A.colU);
    uint2* rb = seg == 0 ? A.rb1A : (seg == 1 ? A.rb1L : A.rb1U);

    // ---- phase A: resolve into LDS + global rb1 ----
    {
        int lr, s, STR;
        if (seg == 0) { lr = tid >> 3; s = tid & 7; STR = 8; }   // 32 rows x 8 slot-threads
        else          { lr = tid >> 2; s = tid & 3; STR = 4; }   // 64 rows x 4 slot-threads
        int row = rowbase + lr;
        u32 jn = cnt[row]; if (jn > CAP) jn = CAP;
        if (s == 0) jns[lr] = jn;
        const u32* cp = col + row * CAP;
        if (seg == 0) {
            for (u32 j = s; j < jn; j += STR) {
                u32 cj = cp[j];
                float w = 1.0f;
                for (u32 j2 = 0; j2 < j; ++j2) if (cp[j2] == cj) { w = 0.0f; break; }
                uint2 v = make_uint2(cj, __float_as_uint(w));
                bkt[lr][j] = v; rb[row * CAP + j] = v;
            }
        } else {
            const u32* ep = (seg == 1 ? A.eidL : A.eidU) + row * CAP;
            const float* wsr = seg == 1 ? A.eal : A.eau;
            for (u32 j = s; j < jn; j += STR) {
                u32 cj = cp[j], ej = ep[j];
                float w = wsr[ej];
                for (u32 j2 = 0; j2 < jn; ++j2)
                    if (j2 != j && cp[j2] == cj && ep[j2] > ej) { w = 0.0f; break; }
                uint2 v = make_uint2(cj, __float_as_uint(w));
                bkt[lr][j] = v; rb[row * CAP + j] = v;
            }
        }
    }
    __syncthreads();

    // ---- phase B: hop-1 gather (width 8) using LDS buckets ----
    int lr2, g;
    if (seg == 0) { lr2 = tid >> 3; g = tid & 7; }   // 32 rows x 8 groups (64 cols)
    else          { lr2 = tid >> 2; g = tid & 3; }   // 64 rows x 4 groups (32 cols)
    const int row2 = rowbase + lr2;
    const u16* src = seg == 0 ? A.Zb1n : A.Zb1e;
    u16* dst = seg == 0 ? A.Zb1n + 64 : (seg == 1 ? A.Zb1e + 32 : A.Zb1e + 96);
    const int ld = seg == 0 ? 192 : 160;
    const u32 jn2 = jns[lr2];
    const u16* srcg = src + g * 8;
    float acc[8] = {};
    for (u32 j = 0; j < jn2; ++j) {
        uint2 q = bkt[lr2][j];
        u16x8 xv = *(const u16x8*)(srcg + (size_t)q.x * ld);
        float w = __uint_as_float(q.y);
#pragma unroll
        for (int e = 0; e < 8; ++e) acc[e] = fmaf(w, bf2f(xv[e]), acc[e]);
    }
    u16x8 o;
#pragma unroll
    for (int e = 0; e < 8; ++e) o[e] = f2bf(acc[e]);
    *(u16x8*)(dst + (size_t)row2 * ld + g * 8) = o;
}

// ================= layer-2 hop-1 spmm: 8 threads/row, dual 8-col slices =================
struct RSeg { const u32* cnt; const uint2* rb; const u16* src; u16* dst; int n; int ld; };
struct Seg3 { RSeg s[3]; };

__device__ __forceinline__ void spmm_row16(const RSeg& s, int t) {
    int row = t >> 3, g = t & 7;
    u32 jn = s.cnt[row]; if (jn > CAP) jn = CAP;
    const uint2* bp = s.rb + (size_t)row * CAP;
    const u16* s0 = s.src + g * 8;
    const u16* s1 = s.src + g * 8 + 64;
    float acc[16] = {};
    u32 j = 0;
    for (; j + 2 <= jn; j += 2) {
        uint2 q0 = bp[j], q1 = bp[j + 1];
        u16x8 a0 = *(const u16x8*)(s0 + (size_t)q0.x * s.ld);
        u16x8 b0 = *(const u16x8*)(s1 + (size_t)q0.x * s.ld);
        u16x8 a1 = *(const u16x8*)(s0 + (size_t)q1.x * s.ld);
        u16x8 b1 = *(const u16x8*)(s1 + (size_t)q1.x * s.ld);
        float w0 = __uint_as_float(q0.y), w1 = __uint_as_float(q1.y);
#pragma unroll
        for (int e = 0; e < 8; ++e) {
            acc[e]     = fmaf(w0, bf2f(a0[e]), acc[e]);
            acc[8 + e] = fmaf(w0, bf2f(b0[e]), acc[8 + e]);
            acc[e]     = fmaf(w1, bf2f(a1[e]), acc[e]);
            acc[8 + e] = fmaf(w1, bf2f(b1[e]), acc[8 + e]);
        }
    }
    for (; j < jn; ++j) {
        uint2 q = bp[j];
        u16x8 a0 = *(const u16x8*)(s0 + (size_t)q.x * s.ld);
        u16x8 b0 = *(const u16x8*)(s1 + (size_t)q.x * s.ld);
        float w = __uint_as_float(q.y);
#pragma unroll
        for (int e = 0; e < 8; ++e) {
            acc[e]     = fmaf(w, bf2f(a0[e]), acc[e]);
            acc[8 + e] = fmaf(w, bf2f(b0[e]), acc[8 + e]);
        }
    }
    u16x8 o0, o1;
#pragma unroll
    for (int e = 0; e < 8; ++e) { o0[e] = f2bf(acc[e]); o1[e] = f2bf(acc[8 + e]); }
    *(u16x8*)(s.dst + (size_t)row * s.ld + g * 8) = o0;
    *(u16x8*)(s.dst + (size_t)row * s.ld + g * 8 + 64) = o1;
}

__global__ __launch_bounds__(256) void spmm16_kernel(Seg3 P) {
    int id = blockIdx.x * blockDim.x + threadIdx.x;
    int base = 0;
#pragma unroll
    for (int i = 0; i < 3; ++i) {
        int n = P.s[i].n;
        if (id < base + n) { spmm_row16(P.s[i], id - base); return; }
        base += n;
    }
}

// ================= K4: layer-1 GEMM with fused hop-2 =================
// 1 tile/block (grid 768), 4 waves x 32 N-cols (256 thr -> 3 waves/SIMD grid-wide).
// 256 threads stage hop-2 (16 thr/row, u16x4 slices); barrier AFTER global-K MFMA.
// node A-tile: k[0,128) global (x|hop1), k[128,192) LDS (hop2)
// edge A-tile: k[0,64) g, k[64,96) LDS(L2), k[96,128) g, k[128,160) LDS(U2)
struct G1Args {
    const u16 *Zb1n, *Zb1e, *nW0T, *eW1T;
    const float *nb0s, *eb0;
    const u32 *cntA, *cntL, *cntU;
    const uint2 *rb1A, *rb1L, *rb1U;
    u16 *Zb2n, *Zb2e;
};

__global__ __launch_bounds__(256) void gemm1_kernel(G1Args A) {
    __shared__ u16 h2[16][72];   // stride 72: fragment reads land 2-way (free)
    const int tid = threadIdx.x;
    const int wv = tid >> 6, lane = tid & 63;
    const int s = blockIdx.x;               // 0..767 tiles (256 node + 512 edge)
    const bool node = s < 256;
    const int m0 = (node ? s : s - 256) * 16;

    // ---- stage hop2 (256 threads, 16 thr/row, 4-col slices) ----
    // node: 64 cols (16 x 4). edge: L2 32 cols (g 0..7), U2 32 cols (g 8..15).
    {
        const int lr = tid >> 4, g = tid & 15;
        const u32* cnt; const uint2* rb; const u16* src; int ld, dc;
        if (node) { cnt = A.cntA; rb = A.rb1A; src = A.Zb1n + 64 + g * 4; ld = 192; dc = g * 4; }
        else {
            const bool isL = g < 8; const int gg = isL ? g : g - 8;
            cnt = isL ? A.cntL : A.cntU; rb = isL ? A.rb1L : A.rb1U;
            src = (isL ? A.Zb1e + 32 : A.Zb1e + 96) + gg * 4; ld = 160;
            dc = (isL ? 0 : 32) + gg * 4;
        }
        const int row = m0 + lr;
        u32 jn = cnt[row]; if (jn > CAP) jn = CAP;
        const uint2* bp = rb + (size_t)row * CAP;
        float acc[4] = {};
        for (u32 j = 0; j < jn; ++j) {
            uint2 qe = bp[j];
            float w = __uint_as_float(qe.y);
            u16x4 a0 = *(const u16x4*)(src + (size_t)qe.x * ld);
#pragma unroll
            for (int e = 0; e < 4; ++e) acc[e] = fmaf(w, bf2f(a0[e]), acc[e]);
        }
        u16x4 o0;
#pragma unroll
        for (int e = 0; e < 4; ++e) o0[e] = f2bf(acc[e]);
        *(u16x4*)&h2[lr][dc] = o0;
    }

    // ---- MFMA GEMM, split-K; wave = 32 N-cols; barrier after global-K ----
    const int c = lane & 15, koff = (lane >> 4) * 8;
    const int n0 = wv * 32;
    f32x4 acc[2] = {};
    const u16* Lr = &h2[c][koff];
    if (node) {
        const u16* Ap = A.Zb1n + (size_t)(m0 + c) * 192 + koff;
        const u16* Wp = A.nW0T + (size_t)(n0 + c) * 192 + koff;
        const size_t ws = (size_t)16 * 192;
#pragma unroll
        for (int k0 = 0; k0 < 128; k0 += 32) {
            bf16x8 af = *(const bf16x8*)(Ap + k0);
#pragma unroll
            for (int nt = 0; nt < 2; ++nt)
                acc[nt] = __builtin_amdgcn_mfma_f32_16x16x32_bf16(af, *(const bf16x8*)(Wp + nt * ws + k0), acc[nt], 0, 0, 0);
        }
        __syncthreads();
#pragma unroll
        for (int k0 = 128; k0 < 192; k0 += 32) {
            bf16x8 af = *(const bf16x8*)(Lr + (k0 - 128));
#pragma unroll
            for (int nt = 0; nt < 2; ++nt)
                acc[nt] = __builtin_amdgcn_mfma_f32_16x16x32_bf16(af, *(const bf16x8*)(Wp + nt * ws + k0), acc[nt], 0, 0, 0);
        }
        const int orow = m0 + (lane >> 4) * 4;
#pragma unroll
        for (int nt = 0; nt < 2; ++nt) {
            int col = n0 + nt * 16 + c;
            float bv = A.nb0s[col];
#pragma unroll
            for (int r = 0; r < 4; ++r)
                A.Zb2n[(size_t)(orow + r) * 384 + col] = f2bf(fmaxf(acc[nt][r] + bv, 0.f));
        }
    } else {
        const u16* Ap = A.Zb1e + (size_t)(m0 + c) * 160 + koff;
        const u16* Wp = A.eW1T + (size_t)(n0 + c) * 160 + koff;
        const size_t ws = (size_t)16 * 160;
        bf16x8 af;
        af = *(const bf16x8*)(Ap + 0);
#pragma unroll
        for (int nt = 0; nt < 2; ++nt)
            acc[nt] = __builtin_amdgcn_mfma_f32_16x16x32_bf16(af, *(const bf16x8*)(Wp + nt * ws + 0), acc[nt], 0, 0, 0);
        af = *(const bf16x8*)(Ap + 32);
#pragma unroll
        for (int nt = 0; nt < 2; ++nt)
            acc[nt] = __builtin_amdgcn_mfma_f32_16x16x32_bf16(af, *(const bf16x8*)(Wp + nt * ws + 32), acc[nt], 0, 0, 0);
        af = *(const bf16x8*)(Ap + 96);
#pragma unroll
        for (int nt = 0; nt < 2; ++nt)
            acc[nt] = __builtin_amdgcn_mfma_f32_16x16x32_bf16(af, *(const bf16x8*)(Wp + nt * ws + 96), acc[nt], 0, 0, 0);
        __syncthreads();
        af = *(const bf16x8*)(Lr + 0);      // L2 hop2, kabs 64
#pragma unroll
        for (int nt = 0; nt < 2; ++nt)
            acc[nt] = __builtin_amdgcn_mfma_f32_16x16x32_bf16(af, *(const bf16x8*)(Wp + nt * ws + 64), acc[nt], 0, 0, 0);
        af = *(const bf16x8*)(Lr + 32);     // U2 hop2, kabs 128
#pragma unroll
        for (int nt = 0; nt < 2; ++nt)
            acc[nt] = __builtin_amdgcn_mfma_f32_16x16x32_bf16(af, *(const bf16x8*)(Wp + nt * ws + 128), acc[nt], 0, 0, 0);
        const int orow = m0 + (lane >> 4) * 4;
#pragma unroll
        for (int nt = 0; nt < 2; ++nt) {
            int col = n0 + nt * 16 + c;
            float bv = A.eb0[col];
#pragma unroll
            for (int r = 0; r < 4; ++r)
                A.Zb2e[(size_t)(orow + r) * 640 + col] = f2bf(fmaxf(acc[nt][r] + bv, 0.f));
        }
    }
}

// ================= K6: layer-2 GEMM + head with fused hop-2 =================
// 1 tile/block (grid 768), 8 waves x 16 N-cols (512 thr). 512 threads stage hop-2
// (32 thr/row: node u16x4 slices, edge u16x8 L/U split). Barrier after global-K.
// node: k[0,256) global (h|hop1), k[256,384) LDS
// edge: k[0,256)+k[384,512) global, then LDS(L2 k[256,384)), LDS(U2 k[512,640))
struct G2Args {
    const u16 *Zb2n, *Zb2e, *nW1T, *eW2T, *fnWT, *feWT;
    const float *nb1s, *eb1, *fnb, *feb;
    const u32 *cntA, *cntL, *cntU;
    const uint2 *rb1A, *rb1L, *rb1U;
    float *outn, *oute;
};

__global__ __launch_bounds__(512) void gemm2_head(G2Args A) {
    __shared__ u16 h2[16][264];   // stride 264: fragment reads land 2-way
    __shared__ u16 g2[16 * 128];
    const int tid = threadIdx.x;
    const int wv = tid >> 6, lane = tid & 63;
    const int s = blockIdx.x;               // 0..767 tiles
    const bool node = s < 256;
    const int m0 = (node ? s : s - 256) * 16;

    // ---- stage hop2 (512 threads, 32 thr/row) ----
    {
        const int lr = tid >> 5, g = tid & 31;
        const int row = m0 + lr;
        if (node) {
            // 128 cols: 32 x 4-col slices
            u32 jn = A.cntA[row]; if (jn > CAP) jn = CAP;
            const uint2* bp = A.rb1A + (size_t)row * CAP;
            const u16* src = A.Zb2n + 128 + g * 4;
            float acc[4] = {};
            for (u32 j = 0; j < jn; ++j) {
                uint2 qe = bp[j];
                float w = __uint_as_float(qe.y);
                u16x4 a0 = *(const u16x4*)(src + (size_t)qe.x * 384);
#pragma unroll
                for (int e = 0; e < 4; ++e) acc[e] = fmaf(w, bf2f(a0[e]), acc[e]);
            }
            u16x4 o0;
#pragma unroll
            for (int e = 0; e < 4; ++e) o0[e] = f2bf(acc[e]);
            *(u16x4*)&h2[lr][g * 4] = o0;
        } else {
            // 256 cols: g<16 -> L2 slice g (8 cols, dc g*8); g>=16 -> U2 (dc 128+(g-16)*8)
            const bool isL = g < 16; const int gg = isL ? g : g - 16;
            const u32* cnt = isL ? A.cntL : A.cntU;
            const uint2* rb = isL ? A.rb1L : A.rb1U;
            const u16* src = (isL ? A.Zb2e + 128 : A.Zb2e + 384) + gg * 8;
            const int dc = (isL ? 0 : 128) + gg * 8;
            u32 jn = cnt[row]; if (jn > CAP) jn = CAP;
            const uint2* bp = rb + (size_t)row * CAP;
            float acc[8] = {};
            for (u32 j = 0; j < jn; ++j) {
                uint2 qe = bp[j];
                float w = __uint_as_float(qe.y);
                u16x8 a0 = *(const u16x8*)(src + (size_t)qe.x * 640);
#pragma unroll
                for (int e = 0; e < 8; ++e) acc[e] = fmaf(w, bf2f(a0[e]), acc[e]);
            }
            u16x8 o0;
#pragma unroll
            for (int e = 0; e < 8; ++e) o0[e] = f2bf(acc[e]);
            *(u16x8*)&h2[lr][dc] = o0;
        }
    }

    // ---- layer-2 GEMM: wave wv computes 16 N-cols; barrier after global-K ----
    const int c = lane & 15, q = lane >> 4, koff = q * 8;
    f32x4 acc = {};
    const u16* Lr = &h2[c][koff];
    const u16* hWT; const float *hB; float* outp;
    if (node) {
        hWT = A.fnWT; hB = A.fnb; outp = A.outn;
        const u16* Ap = A.Zb2n + (size_t)(m0 + c) * 384 + koff;
        const u16* Wp = A.nW1T + (size_t)(wv * 16 + c) * 384 + koff;
#pragma unroll
        for (int k0 = 0; k0 < 256; k0 += 32) {
            bf16x8 af = *(const bf16x8*)(Ap + k0);
            acc = __builtin_amdgcn_mfma_f32_16x16x32_bf16(af, *(const bf16x8*)(Wp + k0), acc, 0, 0, 0);
        }
        __syncthreads();
#pragma unroll
        for (int k0 = 256; k0 < 384; k0 += 32) {
            bf16x8 af = *(const bf16x8*)(Lr + (k0 - 256));
            acc = __builtin_amdgcn_mfma_f32_16x16x32_bf16(af, *(const bf16x8*)(Wp + k0), acc, 0, 0, 0);
        }
        {
            int col = wv * 16 + c;
            float bv = A.nb1s[col];
#pragma unroll
            for (int r = 0; r < 4; ++r)
                g2[(q * 4 + r) * 128 + col] = f2bf(fmaxf(acc[r] + bv, 0.f));
        }
    } else {
        hWT = A.feWT; hB = A.feb; outp = A.oute;
        const u16* Ap = A.Zb2e + (size_t)(m0 + c) * 640 + koff;
        const u16* Wp = A.eW2T + (size_t)(wv * 16 + c) * 640 + koff;
#pragma unroll
        for (int k0 = 0; k0 < 256; k0 += 32) {
            bf16x8 af = *(const bf16x8*)(Ap + k0);
            acc = __builtin_amdgcn_mfma_f32_16x16x32_bf16(af, *(const bf16x8*)(Wp + k0), acc, 0, 0, 0);
        }
#pragma unroll
        for (int k0 = 384; k0 < 512; k0 += 32) {
            bf16x8 af = *(const bf16x8*)(Ap + k0);
            acc = __builtin_amdgcn_mfma_f32_16x16x32_bf16(af, *(const bf16x8*)(Wp + k0), acc, 0, 0, 0);
        }
        __syncthreads();
#pragma unroll
        for (int k0 = 256; k0 < 384; k0 += 32) {
            bf16x8 af = *(const bf16x8*)(Lr + (k0 - 256));
            acc = __builtin_amdgcn_mfma_f32_16x16x32_bf16(af, *(const bf16x8*)(Wp + k0), acc, 0, 0, 0);
        }
#pragma unroll
        for (int k0 = 512; k0 < 640; k0 += 32) {
            bf16x8 af = *(const bf16x8*)(Lr + (128 + k0 - 512));
            acc = __builtin_amdgcn_mfma_f32_16x16x32_bf16(af, *(const bf16x8*)(Wp + k0), acc, 0, 0, 0);
        }
        {
            int col = wv * 16 + c;
            float bv = A.eb1[col];
#pragma unroll
            for (int r = 0; r < 4; ++r)
                g2[(q * 4 + r) * 128 + col] = f2bf(fmaxf(acc[r] + bv, 0.f));
        }
    }
    __syncthreads();

    // ---- head: waves 0..3 produce 16 output cols each ----
    if (wv < 4) {
        f32x4 hacc = {};
        const u16* Hp = hWT + (size_t)(wv * 16 + c) * 128 + koff;
#pragma unroll
        for (int k0 = 0; k0 < 128; k0 += 32) {
            bf16x8 af = *(const bf16x8*)(g2 + c * 128 + koff + k0);
            bf16x8 bf = *(const bf16x8*)(Hp + k0);
            hacc = __builtin_amdgcn_mfma_f32_16x16x32_bf16(af, bf, hacc, 0, 0, 0);
        }
        int col = wv * 16 + c;
        float bv = hB[col];
#pragma unroll
        for (int r = 0; r < 4; ++r)
            outp[(size_t)(m0 + q * 4 + r) * 64 + col] = hacc[r] + bv;
    }
}

// ================= launch =================
extern "C" void kernel_launch(void* const* d_in, const int* in_sizes, int n_in,
                              void* d_out, int out_size, void* d_ws, size_t ws_size,
                              hipStream_t stream)
{
    const float* x    = (const float*)d_in[0];
    const float* ex   = (const float*)d_in[1];
    const int*   nei  = (const int*)d_in[2];
    const int*   eil  = (const int*)d_in[3];
    const float* eal  = (const float*)d_in[4];
    const int*   eiu  = (const int*)d_in[5];
    const float* eau  = (const float*)d_in[6];
    const float* nW0  = (const float*)d_in[7];
    const float* nb0  = (const float*)d_in[8];
    const float* nW1  = (const float*)d_in[9];
    const float* nb1  = (const float*)d_in[10];
    const float* fnW  = (const float*)d_in[11];
    const float* fnb  = (const float*)d_in[12];
    const float* eWl0 = (const float*)d_in[13];
    const float* eWu0 = (const float*)d_in[14];
    const float* eb0  = (const float*)d_in[15];
    const float* eWl1 = (const float*)d_in[16];
    const float* eWu1 = (const float*)d_in[17];
    const float* eb1  = (const float*)d_in[18];
    const float* feW  = (const float*)d_in[19];
    const float* feb  = (const float*)d_in[20];

    char* wsb = (char*)d_ws;
    size_t off = 0;
    auto alloc = [&](size_t bytes) { void* p = wsb + off; off += (bytes + 255) & ~(size_t)255; return p; };

    // ---- zeroed region (single small memset): raw append counters only ----
    u32* cntA = (u32*)alloc(NN * 4);
    u32* cntL = (u32*)alloc(NE * 4);
    u32* cntU = (u32*)alloc(NE * 4);
    size_t zbytes = off;   // ~82 KB

    uint2* rb1A = (uint2*)alloc((size_t)NN * CAP * 8);
    uint2* rb1L = (uint2*)alloc((size_t)NE * CAP * 8);
    uint2* rb1U = (uint2*)alloc((size_t)NE * CAP * 8);

    u32* colA = (u32*)alloc((size_t)NN * CAP * 4);
    u32* colL = (u32*)alloc((size_t)NE * CAP * 4);
    u32* colU = (u32*)alloc((size_t)NE * CAP * 4);
    u32* eidL = (u32*)alloc((size_t)NE * CAP * 4);
    u32* eidU = (u32*)alloc((size_t)NE * CAP * 4);

    u16* Zb1n = (u16*)alloc((size_t)4096 * 192 * 2);
    u16* Zb1e = (u16*)alloc((size_t)8192 * 160 * 2);
    u16* Zb2n = (u16*)alloc((size_t)4096 * 384 * 2);
    u16* Zb2e = (u16*)alloc((size_t)8192 * 640 * 2);

    u16* nW0T = (u16*)alloc((size_t)128 * 192 * 2);
    u16* nW1T = (u16*)alloc((size_t)128 * 384 * 2);
    u16* eW1T = (u16*)alloc((size_t)128 * 160 * 2);
    u16* eW2T = (u16*)alloc((size_t)128 * 640 * 2);
    u16* fnWT = (u16*)alloc((size_t)64 * 128 * 2);
    u16* feWT = (u16*)alloc((size_t)64 * 128 * 2);
    float* nb0s = (float*)alloc(128 * 4);
    float* nb1s = (float*)alloc(128 * 4);

    // ---- D0: zero counters (~82 KB) ----
    hipMemsetAsync(d_ws, 0, zbytes, stream);

    // ---- D1: prep + append ----
    PAArgs PA{x, ex, nW0, nW1, eWl0, eWu0, eWl1, eWu1, fnW, feW, nb0, nb1,
              nei, eil, eiu,
              cntA, cntL, cntU, colA, colL, colU, eidL, eidU,
              Zb1n, Zb1e, nW0T, nW1T, eW1T, eW2T, fnWT, feWT, nb0s, nb1s};
    prep_append<<<dim3(1024), dim3(256), 0, stream>>>(PA);

    // ---- D2: fused resolve + layer-1 hop-1 ----
    RHArgs RH{cntA, cntL, cntU, colA, colL, colU, eidL, eidU, eal, eau,
              rb1A, rb1L, rb1U, Zb1n, Zb1e};
    resolve_hop1<<<dim3(384), dim3(256), 0, stream>>>(RH);

    // ---- D3: layer-1 GEMMs with fused hop-2 (1 tile/block, 4 waves) ----
    {
        G1Args G1{Zb1n, Zb1e, nW0T, eW1T, nb0s, eb0,
                  cntA, cntL, cntU, rb1A, rb1L, rb1U, Zb2n, Zb2e};
        gemm1_kernel<<<dim3(768), dim3(256), 0, stream>>>(G1);
    }

    // ---- D4: layer-2 hop-1 (8 thr/row, dual slices) ----
    {
        Seg3 P;
        P.s[0] = RSeg{cntA, rb1A, Zb2n, Zb2n + 128, NN << 3, 384};
        P.s[1] = RSeg{cntL, rb1L, Zb2e, Zb2e + 128, NE << 3, 640};
        P.s[2] = RSeg{cntU, rb1U, Zb2e, Zb2e + 384, NE << 3, 640};
        int n = (NN << 3) + 2 * (NE << 3);
        spmm16_kernel<<<dim3((n + 255) / 256), dim3(256), 0, stream>>>(P);
    }

    // ---- D5: layer-2 GEMM + head with fused hop-2 (1 tile/block, 8 waves) ----
    {
        G2Args G2{Zb2n, Zb2e, nW1T, eW2T, fnWT, feWT,
                  nb1s, eb1, fnb, feb,
                  cntA, cntL, cntU, rb1A, rb1L, rb1U,
                  (float*)d_out, (float*)d_out + 262144};
        gemm2_head<<<dim3(768), dim3(512), 0, stream>>>(G2);
    }
}

// Round 9
// 159.578 us; speedup vs baseline: 3.4853x; 1.0157x over previous
//
#include <hip/hip_runtime.h>

#define NN 4096
#define NE 8192
#define NLG 32768
#define CAP 32

typedef unsigned int u32;
typedef unsigned short u16;
typedef __attribute__((ext_vector_type(4))) float f32x4;
typedef __attribute__((ext_vector_type(8))) short bf16x8;
typedef __attribute__((ext_vector_type(8))) unsigned short u16x8;
typedef __attribute__((ext_vector_type(4))) unsigned short u16x4;

__device__ __forceinline__ float bf2f(u16 u) { return __uint_as_float(((u32)u) << 16); }
__device__ __forceinline__ u16 f2bf(float f) {
    u32 x = __float_as_uint(f);
    return (u16)((x + 0x7fffu + ((x >> 16) & 1u)) >> 16);  // RNE
}

// ================= K1: prep (converts/transposes/bias) + bucket append, fused =================
struct PAArgs {
    const float *x, *ex;
    const float *nW0, *nW1, *eWl0, *eWu0, *eWl1, *eWu1, *fnW, *feW, *nb0, *nb1;
    const int *nei, *eil, *eiu;
    u32 *cntA, *cntL, *cntU;            // raw counters (zeroed by memset)
    u32 *colA, *colL, *colU, *eidL, *eidU;
    u16 *Zb1n, *Zb1e, *nW0T, *nW1T, *eW1T, *eW2T, *fnWT, *feWT;
    float *nb0s, *nb1s;
};

// 4-wide transpose: thread reads 16B coalesced (4 consecutive nn of src row kk),
// writes 4 elems down dst's contiguous-fast kk dim (L2-absorbed scatter).
__device__ __forceinline__ void wtrK4(const float* src, u16* dst, u32 i, int Kp, int Nw, int ld, int kofs) {
    int n4 = i / Kp, kk = i - n4 * Kp, nn = n4 * 4;
    f32x4 v = *(const f32x4*)(src + (size_t)kk * Nw + nn);
#pragma unroll
    for (int e = 0; e < 4; ++e) dst[(size_t)(nn + e) * ld + kofs + kk] = f2bf(v[e]);
}
__device__ __forceinline__ void wtrS4(const float* sa, const float* sb, u16* dst, u32 i, int Kp, int Nw, int ld) {
    int n4 = i / Kp, kk = i - n4 * Kp, nn = n4 * 4;
    f32x4 va = *(const f32x4*)(sa + (size_t)kk * Nw + nn);
    f32x4 vb = *(const f32x4*)(sb + (size_t)kk * Nw + nn);
#pragma unroll
    for (int e = 0; e < 4; ++e) dst[(size_t)(nn + e) * ld + kk] = f2bf(va[e] + vb[e]);
}

__global__ __launch_bounds__(256) void prep_append(PAArgs A) {
    const u32 gid = blockIdx.x * blockDim.x + threadIdx.x;
    const u32 gsz = gridDim.x * blockDim.x;
    const u32 C0 = 65536;                 // x conv (f32x4 units)
    const u32 C1 = C0 + 65536;            // ex conv
    const u32 C2 = C1 + 6144;             // nW0T (Kp=192, /4)
    const u32 C3 = C2 + 12288;            // nW1T (Kp=384, /4)
    const u32 C4 = C3 + 1024;             // eW1T sum block (Kp=32, /4)
    const u32 C5 = C4 + 1024;             // eWl0 k=1
    const u32 C6 = C5 + 1024;             // eWl0 k=2
    const u32 C7 = C6 + 1024;             // eWu0 k=1
    const u32 C8 = C7 + 1024;             // eWu0 k=2
    const u32 C9 = C8 + 4096;             // eW2T sum block (Kp=128, /4)
    const u32 C10 = C9 + 4096;            // eWl1 k=1
    const u32 C11 = C10 + 4096;           // eWl1 k=2
    const u32 C12 = C11 + 4096;           // eWu1 k=1
    const u32 C13 = C12 + 4096;           // eWu1 k=2
    const u32 C14 = C13 + 2048;           // fnWT
    const u32 C15 = C14 + 2048;           // feWT
    const u32 C16 = C15 + 256;            // bias sums
    const u32 C17 = C16 + (NE + 2 * NLG); // append
    for (u32 i = gid; i < C17; i += gsz) {
        if (i < C0) {
            u32 t = i; int r = t >> 4, c4 = t & 15;
            f32x4 v = *(const f32x4*)(A.x + (size_t)t * 4);
            u16x4 o;
#pragma unroll
            for (int e = 0; e < 4; ++e) o[e] = f2bf(v[e]);
            *(u16x4*)(A.Zb1n + (size_t)r * 192 + c4 * 4) = o;
        } else if (i < C1) {
            u32 t = i - C0; int r = t >> 3, c4 = t & 7;
            f32x4 v = *(const f32x4*)(A.ex + (size_t)t * 4);
            u16x4 o;
#pragma unroll
            for (int e = 0; e < 4; ++e) o[e] = f2bf(v[e]);
            *(u16x4*)(A.Zb1e + (size_t)r * 160 + c4 * 4) = o;
        }
        else if (i < C2)  wtrK4(A.nW0, A.nW0T, i - C1, 192, 128, 192, 0);
        else if (i < C3)  wtrK4(A.nW1, A.nW1T, i - C2, 384, 128, 384, 0);
        else if (i < C4)  wtrS4(A.eWl0, A.eWu0, A.eW1T, i - C3, 32, 128, 160);
        else if (i < C5)  wtrK4(A.eWl0 + 32 * 128,     A.eW1T, i - C4, 32, 128, 160, 32);
        else if (i < C6)  wtrK4(A.eWl0 + 2 * 32 * 128, A.eW1T, i - C5, 32, 128, 160, 64);
        else if (i < C7)  wtrK4(A.eWu0 + 32 * 128,     A.eW1T, i - C6, 32, 128, 160, 96);
        else if (i < C8)  wtrK4(A.eWu0 + 2 * 32 * 128, A.eW1T, i - C7, 32, 128, 160, 128);
        else if (i < C9)  wtrS4(A.eWl1, A.eWu1, A.eW2T, i - C8, 128, 128, 640);
        else if (i < C10) wtrK4(A.eWl1 + 128 * 128,     A.eW2T, i - C9, 128, 128, 640, 128);
        else if (i < C11) wtrK4(A.eWl1 + 2 * 128 * 128, A.eW2T, i - C10, 128, 128, 640, 256);
        else if (i < C12) wtrK4(A.eWu1 + 128 * 128,     A.eW2T, i - C11, 128, 128, 640, 384);
        else if (i < C13) wtrK4(A.eWu1 + 2 * 128 * 128, A.eW2T, i - C12, 128, 128, 640, 512);
        else if (i < C14) wtrK4(A.fnW, A.fnWT, i - C13, 128, 64, 128, 0);
        else if (i < C15) wtrK4(A.feW, A.feWT, i - C14, 128, 64, 128, 0);
        else if (i < C16) {
            u32 t = i - C15;
            if (t < 128) { float s = 0.f; for (int k = 0; k < 3; ++k) s += A.nb0[k * 128 + t]; A.nb0s[t] = s; }
            else { t -= 128; float s = 0.f; for (int k = 0; k < 3; ++k) s += A.nb1[k * 128 + t]; A.nb1s[t] = s; }
        } else {
            u32 t = i - C16;
            if (t < NE) {
                int r = A.nei[t];
                u32 p = atomicAdd(&A.cntA[r], 1u);
                if (p < CAP) A.colA[r * CAP + p] = (u32)A.nei[NE + t];
            } else if (t < NE + NLG) {
                u32 e = t - NE;
                int r = A.eil[e];
                u32 p = atomicAdd(&A.cntL[r], 1u);
                if (p < CAP) { A.colL[r * CAP + p] = (u32)A.eil[NLG + e]; A.eidL[r * CAP + p] = e; }
            } else {
                u32 e = t - NE - NLG;
                int r = A.eiu[e];
                u32 p = atomicAdd(&A.cntU[r], 1u);
                if (p < CAP) { A.colU[r * CAP + p] = (u32)A.eiu[NLG + e]; A.eidU[r * CAP + p] = e; }
            }
        }
    }
}

// ================= K2: fused resolve + layer-1 hop-1 spmm =================
// Uniform 32-row blocks: A 128 + L 256 + U 256 = 640 blocks, 8 slot-threads/row.
// In-place semantics: loser/dup slots get w=0. A: first-slot-wins. L/U: max-eid-wins.
struct RHArgs {
    const u32 *cntA, *cntL, *cntU;
    const u32 *colA, *colL, *colU, *eidL, *eidU;
    const float *eal, *eau;
    uint2 *rb1A, *rb1L, *rb1U;
    u16 *Zb1n, *Zb1e;
};

__global__ __launch_bounds__(256) void resolve_hop1(RHArgs A) {
    __shared__ uint2 bkt[32][33];   // +1 pad: breaks 256B-stride bank aliasing
    __shared__ u32 jns[32];
    const int b = blockIdx.x, tid = threadIdx.x;
    const int seg = (b < 128) ? 0 : (b < 384 ? 1 : 2);   // A / L / U
    const int rowbase = (seg == 0 ? b : (seg == 1 ? b - 128 : b - 384)) * 32;
    const u32* cnt = seg == 0 ? A.cntA : (seg == 1 ? A.cntL : A.cntU);
    const u32* col = seg == 0 ? A.colA : (seg == 1 ? A.colL : A.colU);
    uint2* rb = seg == 0 ? A.rb1A : (seg == 1 ? A.rb1L : A.rb1U);

    // ---- phase A: resolve into LDS + global rb1 (8 slot-threads/row) ----
    {
        const int lr = tid >> 3, s = tid & 7;
        const int row = rowbase + lr;
        u32 jn = cnt[row]; if (jn > CAP) jn = CAP;
        if (s == 0) jns[lr] = jn;
        const u32* cp = col + row * CAP;
        if (seg == 0) {
            for (u32 j = s; j < jn; j += 8) {
                u32 cj = cp[j];
                float w = 1.0f;
                for (u32 j2 = 0; j2 < j; ++j2) if (cp[j2] == cj) { w = 0.0f; break; }
                uint2 v = make_uint2(cj, __float_as_uint(w));
                bkt[lr][j] = v; rb[row * CAP + j] = v;
            }
        } else {
            const u32* ep = (seg == 1 ? A.eidL : A.eidU) + row * CAP;
            const float* wsr = seg == 1 ? A.eal : A.eau;
            for (u32 j = s; j < jn; j += 8) {
                u32 cj = cp[j], ej = ep[j];
                float w = wsr[ej];
                for (u32 j2 = 0; j2 < jn; ++j2)
                    if (j2 != j && cp[j2] == cj && ep[j2] > ej) { w = 0.0f; break; }
                uint2 v = make_uint2(cj, __float_as_uint(w));
                bkt[lr][j] = v; rb[row * CAP + j] = v;
            }
        }
    }
    __syncthreads();

    // ---- phase B: hop-1 gather using LDS buckets (8 col-groups/row) ----
    const int lr2 = tid >> 3, g = tid & 7;
    const int row2 = rowbase + lr2;
    const u32 jn2 = jns[lr2];
    if (seg == 0) {
        // node: 64 cols = 8 groups x 8
        const u16* srcg = A.Zb1n + g * 8;
        float acc[8] = {};
        for (u32 j = 0; j < jn2; ++j) {
            uint2 q = bkt[lr2][j];
            u16x8 xv = *(const u16x8*)(srcg + (size_t)q.x * 192);
            float w = __uint_as_float(q.y);
#pragma unroll
            for (int e = 0; e < 8; ++e) acc[e] = fmaf(w, bf2f(xv[e]), acc[e]);
        }
        u16x8 o;
#pragma unroll
        for (int e = 0; e < 8; ++e) o[e] = f2bf(acc[e]);
        *(u16x8*)(A.Zb1n + 64 + (size_t)row2 * 192 + g * 8) = o;
    } else {
        // edge: 32 cols = 8 groups x 4
        const u16* srcg = A.Zb1e + g * 4;
        u16* dst = seg == 1 ? A.Zb1e + 32 : A.Zb1e + 96;
        float acc[4] = {};
        for (u32 j = 0; j < jn2; ++j) {
            uint2 q = bkt[lr2][j];
            u16x4 xv = *(const u16x4*)(srcg + (size_t)q.x * 160);
            float w = __uint_as_float(q.y);
#pragma unroll
            for (int e = 0; e < 4; ++e) acc[e] = fmaf(w, bf2f(xv[e]), acc[e]);
        }
        u16x4 o;
#pragma unroll
        for (int e = 0; e < 4; ++e) o[e] = f2bf(acc[e]);
        *(u16x4*)(dst + (size_t)row2 * 160 + g * 4) = o;
    }
}

// ================= layer-2 hop-1 spmm: 8 threads/row, dual 8-col slices =================
struct RSeg { const u32* cnt; const uint2* rb; const u16* src; u16* dst; int n; int ld; };
struct Seg3 { RSeg s[3]; };

__device__ __forceinline__ void spmm_row16(const RSeg& s, int t) {
    int row = t >> 3, g = t & 7;
    u32 jn = s.cnt[row]; if (jn > CAP) jn = CAP;
    const uint2* bp = s.rb + (size_t)row * CAP;
    const u16* s0 = s.src + g * 8;
    const u16* s1 = s.src + g * 8 + 64;
    float acc[16] = {};
    u32 j = 0;
    for (; j + 2 <= jn; j += 2) {
        uint2 q0 = bp[j], q1 = bp[j + 1];
        u16x8 a0 = *(const u16x8*)(s0 + (size_t)q0.x * s.ld);
        u16x8 b0 = *(const u16x8*)(s1 + (size_t)q0.x * s.ld);
        u16x8 a1 = *(const u16x8*)(s0 + (size_t)q1.x * s.ld);
        u16x8 b1 = *(const u16x8*)(s1 + (size_t)q1.x * s.ld);
        float w0 = __uint_as_float(q0.y), w1 = __uint_as_float(q1.y);
#pragma unroll
        for (int e = 0; e < 8; ++e) {
            acc[e]     = fmaf(w0, bf2f(a0[e]), acc[e]);
            acc[8 + e] = fmaf(w0, bf2f(b0[e]), acc[8 + e]);
            acc[e]     = fmaf(w1, bf2f(a1[e]), acc[e]);
            acc[8 + e] = fmaf(w1, bf2f(b1[e]), acc[8 + e]);
        }
    }
    for (; j < jn; ++j) {
        uint2 q = bp[j];
        u16x8 a0 = *(const u16x8*)(s0 + (size_t)q.x * s.ld);
        u16x8 b0 = *(const u16x8*)(s1 + (size_t)q.x * s.ld);
        float w = __uint_as_float(q.y);
#pragma unroll
        for (int e = 0; e < 8; ++e) {
            acc[e]     = fmaf(w, bf2f(a0[e]), acc[e]);
            acc[8 + e] = fmaf(w, bf2f(b0[e]), acc[8 + e]);
        }
    }
    u16x8 o0, o1;
#pragma unroll
    for (int e = 0; e < 8; ++e) { o0[e] = f2bf(acc[e]); o1[e] = f2bf(acc[8 + e]); }
    *(u16x8*)(s.dst + (size_t)row * s.ld + g * 8) = o0;
    *(u16x8*)(s.dst + (size_t)row * s.ld + g * 8 + 64) = o1;
}

__global__ __launch_bounds__(256) void spmm16_kernel(Seg3 P) {
    int id = blockIdx.x * blockDim.x + threadIdx.x;
    int base = 0;
#pragma unroll
    for (int i = 0; i < 3; ++i) {
        int n = P.s[i].n;
        if (id < base + n) { spmm_row16(P.s[i], id - base); return; }
        base += n;
    }
}

// ================= K4: layer-1 GEMM with fused hop-2 =================
// 1 tile/block (grid 768, striped node/edge), 4 waves x 32 N-cols.
// 256 threads stage hop-2 (16 thr/row, u16x4 slices); barrier AFTER global-K MFMA.
// node A-tile: k[0,128) global (x|hop1), k[128,192) LDS (hop2)
// edge A-tile: k[0,64) g, k[64,96) LDS(L2), k[96,128) g, k[128,160) LDS(U2)
struct G1Args {
    const u16 *Zb1n, *Zb1e, *nW0T, *eW1T;
    const float *nb0s, *eb0;
    const u32 *cntA, *cntL, *cntU;
    const uint2 *rb1A, *rb1L, *rb1U;
    u16 *Zb2n, *Zb2e;
};

__global__ __launch_bounds__(256) void gemm1_kernel(G1Args A) {
    __shared__ u16 h2[16][72];   // stride 72: fragment reads land 2-way (free)
    const int tid = threadIdx.x;
    const int wv = tid >> 6, lane = tid & 63;
    const int bid = blockIdx.x;
    const int s = (bid % 3) * 256 + bid / 3;   // stripe: mix node/edge through launch order
    const bool node = s < 256;
    const int m0 = (node ? s : s - 256) * 16;

    // ---- stage hop2 (256 threads, 16 thr/row, 4-col slices) ----
    // node: 64 cols (16 x 4). edge: L2 32 cols (g 0..7), U2 32 cols (g 8..15).
    {
        const int lr = tid >> 4, g = tid & 15;
        const u32* cnt; const uint2* rb; const u16* src; int ld, dc;
        if (node) { cnt = A.cntA; rb = A.rb1A; src = A.Zb1n + 64 + g * 4; ld = 192; dc = g * 4; }
        else {
            const bool isL = g < 8; const int gg = isL ? g : g - 8;
            cnt = isL ? A.cntL : A.cntU; rb = isL ? A.rb1L : A.rb1U;
            src = (isL ? A.Zb1e + 32 : A.Zb1e + 96) + gg * 4; ld = 160;
            dc = (isL ? 0 : 32) + gg * 4;
        }
        const int row = m0 + lr;
        u32 jn = cnt[row]; if (jn > CAP) jn = CAP;
        const uint2* bp = rb + (size_t)row * CAP;
        float acc[4] = {};
        for (u32 j = 0; j < jn; ++j) {
            uint2 qe = bp[j];
            float w = __uint_as_float(qe.y);
            u16x4 a0 = *(const u16x4*)(src + (size_t)qe.x * ld);
#pragma unroll
            for (int e = 0; e < 4; ++e) acc[e] = fmaf(w, bf2f(a0[e]), acc[e]);
        }
        u16x4 o0;
#pragma unroll
        for (int e = 0; e < 4; ++e) o0[e] = f2bf(acc[e]);
        *(u16x4*)&h2[lr][dc] = o0;
    }

    // ---- MFMA GEMM, split-K; wave = 32 N-cols; barrier after global-K ----
    const int c = lane & 15, koff = (lane >> 4) * 8;
    const int n0 = wv * 32;
    f32x4 acc[2] = {};
    const u16* Lr = &h2[c][koff];
    if (node) {
        const u16* Ap = A.Zb1n + (size_t)(m0 + c) * 192 + koff;
        const u16* Wp = A.nW0T + (size_t)(n0 + c) * 192 + koff;
        const size_t ws = (size_t)16 * 192;
#pragma unroll
        for (int k0 = 0; k0 < 128; k0 += 32) {
            bf16x8 af = *(const bf16x8*)(Ap + k0);
#pragma unroll
            for (int nt = 0; nt < 2; ++nt)
                acc[nt] = __builtin_amdgcn_mfma_f32_16x16x32_bf16(af, *(const bf16x8*)(Wp + nt * ws + k0), acc[nt], 0, 0, 0);
        }
        __syncthreads();
#pragma unroll
        for (int k0 = 128; k0 < 192; k0 += 32) {
            bf16x8 af = *(const bf16x8*)(Lr + (k0 - 128));
#pragma unroll
            for (int nt = 0; nt < 2; ++nt)
                acc[nt] = __builtin_amdgcn_mfma_f32_16x16x32_bf16(af, *(const bf16x8*)(Wp + nt * ws + k0), acc[nt], 0, 0, 0);
        }
        const int orow = m0 + (lane >> 4) * 4;
#pragma unroll
        for (int nt = 0; nt < 2; ++nt) {
            int col = n0 + nt * 16 + c;
            float bv = A.nb0s[col];
#pragma unroll
            for (int r = 0; r < 4; ++r)
                A.Zb2n[(size_t)(orow + r) * 384 + col] = f2bf(fmaxf(acc[nt][r] + bv, 0.f));
        }
    } else {
        const u16* Ap = A.Zb1e + (size_t)(m0 + c) * 160 + koff;
        const u16* Wp = A.eW1T + (size_t)(n0 + c) * 160 + koff;
        const size_t ws = (size_t)16 * 160;
        bf16x8 af;
        af = *(const bf16x8*)(Ap + 0);
#pragma unroll
        for (int nt = 0; nt < 2; ++nt)
            acc[nt] = __builtin_amdgcn_mfma_f32_16x16x32_bf16(af, *(const bf16x8*)(Wp + nt * ws + 0), acc[nt], 0, 0, 0);
        af = *(const bf16x8*)(Ap + 32);
#pragma unroll
        for (int nt = 0; nt < 2; ++nt)
            acc[nt] = __builtin_amdgcn_mfma_f32_16x16x32_bf16(af, *(const bf16x8*)(Wp + nt * ws + 32), acc[nt], 0, 0, 0);
        af = *(const bf16x8*)(Ap + 96);
#pragma unroll
        for (int nt = 0; nt < 2; ++nt)
            acc[nt] = __builtin_amdgcn_mfma_f32_16x16x32_bf16(af, *(const bf16x8*)(Wp + nt * ws + 96), acc[nt], 0, 0, 0);
        __syncthreads();
        af = *(const bf16x8*)(Lr + 0);      // L2 hop2, kabs 64
#pragma unroll
        for (int nt = 0; nt < 2; ++nt)
            acc[nt] = __builtin_amdgcn_mfma_f32_16x16x32_bf16(af, *(const bf16x8*)(Wp + nt * ws + 64), acc[nt], 0, 0, 0);
        af = *(const bf16x8*)(Lr + 32);     // U2 hop2, kabs 128
#pragma unroll
        for (int nt = 0; nt < 2; ++nt)
            acc[nt] = __builtin_amdgcn_mfma_f32_16x16x32_bf16(af, *(const bf16x8*)(Wp + nt * ws + 128), acc[nt], 0, 0, 0);
        const int orow = m0 + (lane >> 4) * 4;
#pragma unroll
        for (int nt = 0; nt < 2; ++nt) {
            int col = n0 + nt * 16 + c;
            float bv = A.eb0[col];
#pragma unroll
            for (int r = 0; r < 4; ++r)
                A.Zb2e[(size_t)(orow + r) * 640 + col] = f2bf(fmaxf(acc[nt][r] + bv, 0.f));
        }
    }
}

// ================= K6: layer-2 GEMM + head with fused hop-2 =================
// 1 tile/block (grid 768, striped), 8 waves x 16 N-cols (512 thr). 512 threads stage
// hop-2 (32 thr/row). Barrier after global-K.
// node: k[0,256) global (h|hop1), k[256,384) LDS
// edge: k[0,256)+k[384,512) global, then LDS(L2 k[256,384)), LDS(U2 k[512,640))
struct G2Args {
    const u16 *Zb2n, *Zb2e, *nW1T, *eW2T, *fnWT, *feWT;
    const float *nb1s, *eb1, *fnb, *feb;
    const u32 *cntA, *cntL, *cntU;
    const uint2 *rb1A, *rb1L, *rb1U;
    float *outn, *oute;
};

__global__ __launch_bounds__(512) void gemm2_head(G2Args A) {
    __shared__ u16 h2[16][264];   // stride 264: fragment reads land 2-way
    __shared__ u16 g2[16 * 128];
    const int tid = threadIdx.x;
    const int wv = tid >> 6, lane = tid & 63;
    const int bid = blockIdx.x;
    const int s = (bid % 3) * 256 + bid / 3;   // stripe: mix node/edge through launch order
    const bool node = s < 256;
    const int m0 = (node ? s : s - 256) * 16;

    // ---- stage hop2 (512 threads, 32 thr/row) ----
    {
        const int lr = tid >> 5, g = tid & 31;
        const int row = m0 + lr;
        if (node) {
            // 128 cols: 32 x 4-col slices
            u32 jn = A.cntA[row]; if (jn > CAP) jn = CAP;
            const uint2* bp = A.rb1A + (size_t)row * CAP;
            const u16* src = A.Zb2n + 128 + g * 4;
            float acc[4] = {};
            for (u32 j = 0; j < jn; ++j) {
                uint2 qe = bp[j];
                float w = __uint_as_float(qe.y);
                u16x4 a0 = *(const u16x4*)(src + (size_t)qe.x * 384);
#pragma unroll
                for (int e = 0; e < 4; ++e) acc[e] = fmaf(w, bf2f(a0[e]), acc[e]);
            }
            u16x4 o0;
#pragma unroll
            for (int e = 0; e < 4; ++e) o0[e] = f2bf(acc[e]);
            *(u16x4*)&h2[lr][g * 4] = o0;
        } else {
            // 256 cols: g<16 -> L2 slice g (8 cols, dc g*8); g>=16 -> U2 (dc 128+(g-16)*8)
            const bool isL = g < 16; const int gg = isL ? g : g - 16;
            const u32* cnt = isL ? A.cntL : A.cntU;
            const uint2* rb = isL ? A.rb1L : A.rb1U;
            const u16* src = (isL ? A.Zb2e + 128 : A.Zb2e + 384) + gg * 8;
            const int dc = (isL ? 0 : 128) + gg * 8;
            u32 jn = cnt[row]; if (jn > CAP) jn = CAP;
            const uint2* bp = rb + (size_t)row * CAP;
            float acc[8] = {};
            for (u32 j = 0; j < jn; ++j) {
                uint2 qe = bp[j];
                float w = __uint_as_float(qe.y);
                u16x8 a0 = *(const u16x8*)(src + (size_t)qe.x * 640);
#pragma unroll
                for (int e = 0; e < 8; ++e) acc[e] = fmaf(w, bf2f(a0[e]), acc[e]);
            }
            u16x8 o0;
#pragma unroll
            for (int e = 0; e < 8; ++e) o0[e] = f2bf(acc[e]);
            *(u16x8*)&h2[lr][dc] = o0;
        }
    }

    // ---- layer-2 GEMM: wave wv computes 16 N-cols; barrier after global-K ----
    const int c = lane & 15, q = lane >> 4, koff = q * 8;
    f32x4 acc = {};
    const u16* Lr = &h2[c][koff];
    const u16* hWT; const float *hB; float* outp;
    if (node) {
        hWT = A.fnWT; hB = A.fnb; outp = A.outn;
        const u16* Ap = A.Zb2n + (size_t)(m0 + c) * 384 + koff;
        const u16* Wp = A.nW1T + (size_t)(wv * 16 + c) * 384 + koff;
#pragma unroll
        for (int k0 = 0; k0 < 256; k0 += 32) {
            bf16x8 af = *(const bf16x8*)(Ap + k0);
            acc = __builtin_amdgcn_mfma_f32_16x16x32_bf16(af, *(const bf16x8*)(Wp + k0), acc, 0, 0, 0);
        }
        __syncthreads();
#pragma unroll
        for (int k0 = 256; k0 < 384; k0 += 32) {
            bf16x8 af = *(const bf16x8*)(Lr + (k0 - 256));
            acc = __builtin_amdgcn_mfma_f32_16x16x32_bf16(af, *(const bf16x8*)(Wp + k0), acc, 0, 0, 0);
        }
        {
            int col = wv * 16 + c;
            float bv = A.nb1s[col];
#pragma unroll
            for (int r = 0; r < 4; ++r)
                g2[(q * 4 + r) * 128 + col] = f2bf(fmaxf(acc[r] + bv, 0.f));
        }
    } else {
        hWT = A.feWT; hB = A.feb; outp = A.oute;
        const u16* Ap = A.Zb2e + (size_t)(m0 + c) * 640 + koff;
        const u16* Wp = A.eW2T + (size_t)(wv * 16 + c) * 640 + koff;
#pragma unroll
        for (int k0 = 0; k0 < 256; k0 += 32) {
            bf16x8 af = *(const bf16x8*)(Ap + k0);
            acc = __builtin_amdgcn_mfma_f32_16x16x32_bf16(af, *(const bf16x8*)(Wp + k0), acc, 0, 0, 0);
        }
#pragma unroll
        for (int k0 = 384; k0 < 512; k0 += 32) {
            bf16x8 af = *(const bf16x8*)(Ap + k0);
            acc = __builtin_amdgcn_mfma_f32_16x16x32_bf16(af, *(const bf16x8*)(Wp + k0), acc, 0, 0, 0);
        }
        __syncthreads();
#pragma unroll
        for (int k0 = 256; k0 < 384; k0 += 32) {
            bf16x8 af = *(const bf16x8*)(Lr + (k0 - 256));
            acc = __builtin_amdgcn_mfma_f32_16x16x32_bf16(af, *(const bf16x8*)(Wp + k0), acc, 0, 0, 0);
        }
#pragma unroll
        for (int k0 = 512; k0 < 640; k0 += 32) {
            bf16x8 af = *(const bf16x8*)(Lr + (128 + k0 - 512));
            acc = __builtin_amdgcn_mfma_f32_16x16x32_bf16(af, *(const bf16x8*)(Wp + k0), acc, 0, 0, 0);
        }
        {
            int col = wv * 16 + c;
            float bv = A.eb1[col];
#pragma unroll
            for (int r = 0; r < 4; ++r)
                g2[(q * 4 + r) * 128 + col] = f2bf(fmaxf(acc[r] + bv, 0.f));
        }
    }
    __syncthreads();

    // ---- head: waves 0..3 produce 16 output cols each ----
    if (wv < 4) {
        f32x4 hacc = {};
        const u16* Hp = hWT + (size_t)(wv * 16 + c) * 128 + koff;
#pragma unroll
        for (int k0 = 0; k0 < 128; k0 += 32) {
            bf16x8 af = *(const bf16x8*)(g2 + c * 128 + koff + k0);
            bf16x8 bf = *(const bf16x8*)(Hp + k0);
            hacc = __builtin_amdgcn_mfma_f32_16x16x32_bf16(af, bf, hacc, 0, 0, 0);
        }
        int col = wv * 16 + c;
        float bv = hB[col];
#pragma unroll
        for (int r = 0; r < 4; ++r)
            outp[(size_t)(m0 + q * 4 + r) * 64 + col] = hacc[r] + bv;
    }
}

// ================= launch =================
extern "C" void kernel_launch(void* const* d_in, const int* in_sizes, int n_in,
                              void* d_out, int out_size, void* d_ws, size_t ws_size,
                              hipStream_t stream)
{
    const float* x    = (const float*)d_in[0];
    const float* ex   = (const float*)d_in[1];
    const int*   nei  = (const int*)d_in[2];
    const int*   eil  = (const int*)d_in[3];
    const float* eal  = (const float*)d_in[4];
    const int*   eiu  = (const int*)d_in[5];
    const float* eau  = (const float*)d_in[6];
    const float* nW0  = (const float*)d_in[7];
    const float* nb0  = (const float*)d_in[8];
    const float* nW1  = (const float*)d_in[9];
    const float* nb1  = (const float*)d_in[10];
    const float* fnW  = (const float*)d_in[11];
    const float* fnb  = (const float*)d_in[12];
    const float* eWl0 = (const float*)d_in[13];
    const float* eWu0 = (const float*)d_in[14];
    const float* eb0  = (const float*)d_in[15];
    const float* eWl1 = (const float*)d_in[16];
    const float* eWu1 = (const float*)d_in[17];
    const float* eb1  = (const float*)d_in[18];
    const float* feW  = (const float*)d_in[19];
    const float* feb  = (const float*)d_in[20];

    char* wsb = (char*)d_ws;
    size_t off = 0;
    auto alloc = [&](size_t bytes) { void* p = wsb + off; off += (bytes + 255) & ~(size_t)255; return p; };

    // ---- zeroed region (single small memset): raw append counters only ----
    u32* cntA = (u32*)alloc(NN * 4);
    u32* cntL = (u32*)alloc(NE * 4);
    u32* cntU = (u32*)alloc(NE * 4);
    size_t zbytes = off;   // ~82 KB

    uint2* rb1A = (uint2*)alloc((size_t)NN * CAP * 8);
    uint2* rb1L = (uint2*)alloc((size_t)NE * CAP * 8);
    uint2* rb1U = (uint2*)alloc((size_t)NE * CAP * 8);

    u32* colA = (u32*)alloc((size_t)NN * CAP * 4);
    u32* colL = (u32*)alloc((size_t)NE * CAP * 4);
    u32* colU = (u32*)alloc((size_t)NE * CAP * 4);
    u32* eidL = (u32*)alloc((size_t)NE * CAP * 4);
    u32* eidU = (u32*)alloc((size_t)NE * CAP * 4);

    u16* Zb1n = (u16*)alloc((size_t)4096 * 192 * 2);
    u16* Zb1e = (u16*)alloc((size_t)8192 * 160 * 2);
    u16* Zb2n = (u16*)alloc((size_t)4096 * 384 * 2);
    u16* Zb2e = (u16*)alloc((size_t)8192 * 640 * 2);

    u16* nW0T = (u16*)alloc((size_t)128 * 192 * 2);
    u16* nW1T = (u16*)alloc((size_t)128 * 384 * 2);
    u16* eW1T = (u16*)alloc((size_t)128 * 160 * 2);
    u16* eW2T = (u16*)alloc((size_t)128 * 640 * 2);
    u16* fnWT = (u16*)alloc((size_t)64 * 128 * 2);
    u16* feWT = (u16*)alloc((size_t)64 * 128 * 2);
    float* nb0s = (float*)alloc(128 * 4);
    float* nb1s = (float*)alloc(128 * 4);

    // ---- D0: zero counters (~82 KB) ----
    hipMemsetAsync(d_ws, 0, zbytes, stream);

    // ---- D1: prep + append ----
    PAArgs PA{x, ex, nW0, nW1, eWl0, eWu0, eWl1, eWu1, fnW, feW, nb0, nb1,
              nei, eil, eiu,
              cntA, cntL, cntU, colA, colL, colU, eidL, eidU,
              Zb1n, Zb1e, nW0T, nW1T, eW1T, eW2T, fnWT, feWT, nb0s, nb1s};
    prep_append<<<dim3(1024), dim3(256), 0, stream>>>(PA);

    // ---- D2: fused resolve + layer-1 hop-1 (640 x 32-row blocks) ----
    RHArgs RH{cntA, cntL, cntU, colA, colL, colU, eidL, eidU, eal, eau,
              rb1A, rb1L, rb1U, Zb1n, Zb1e};
    resolve_hop1<<<dim3(640), dim3(256), 0, stream>>>(RH);

    // ---- D3: layer-1 GEMMs with fused hop-2 (striped tiles, 4 waves) ----
    {
        G1Args G1{Zb1n, Zb1e, nW0T, eW1T, nb0s, eb0,
                  cntA, cntL, cntU, rb1A, rb1L, rb1U, Zb2n, Zb2e};
        gemm1_kernel<<<dim3(768), dim3(256), 0, stream>>>(G1);
    }

    // ---- D4: layer-2 hop-1 (8 thr/row, dual slices) ----
    {
        Seg3 P;
        P.s[0] = RSeg{cntA, rb1A, Zb2n, Zb2n + 128, NN << 3, 384};
        P.s[1] = RSeg{cntL, rb1L, Zb2e, Zb2e + 128, NE << 3, 640};
        P.s[2] = RSeg{cntU, rb1U, Zb2e, Zb2e + 384, NE << 3, 640};
        int n = (NN << 3) + 2 * (NE << 3);
        spmm16_kernel<<<dim3((n + 255) / 256), dim3(256), 0, stream>>>(P);
    }

    // ---- D5: layer-2 GEMM + head with fused hop-2 (striped tiles, 8 waves) ----
    {
        G2Args G2{Zb2n, Zb2e, nW1T, eW2T, fnWT, feWT,
                  nb1s, eb1, fnb, feb,
                  cntA, cntL, cntU, rb1A, rb1L, rb1U,
                  (float*)d_out, (float*)d_out + 262144};
        gemm2_head<<<dim3(768), dim3(512), 0, stream>>>(G2);
    }
}